// Round 1
// baseline (345.591 us; speedup 1.0000x reference)
//
#include <hip/hip_runtime.h>

#define NUM_HEADS 16
#define HEAD_DIM 64
#define DIM 1024
#define NTOK 2048
#define MTOT 4096

typedef __attribute__((ext_vector_type(8))) short bf16x8;
typedef __attribute__((ext_vector_type(4))) float f32x4;

__device__ __forceinline__ unsigned short f2bf(float f) {
    union { float f; unsigned int u; } v; v.f = f;
    unsigned int r = v.u + 0x7FFFu + ((v.u >> 16) & 1u);
    return (unsigned short)(r >> 16);
}

// ---------------- Kernel 1: QKV GEMM + bias + RoPE + layout ----------------
// out tiles: 64 rows (tokens) x 64 cols (one head of q, k, or v)
// q,k -> [b,h][n][d] bf16 (q scaled by 0.125); v -> [b,h][d][n] bf16 (transposed)
__global__ __launch_bounds__(256) void k_qkv_rope(
    const float* __restrict__ x, const float* __restrict__ w,
    const float* __restrict__ bias, const float* __restrict__ rcos,
    const float* __restrict__ rsin,
    unsigned short* __restrict__ qb, unsigned short* __restrict__ kb,
    unsigned short* __restrict__ vtb)
{
    __shared__ __align__(16) unsigned short atile[64][64];
    __shared__ __align__(16) unsigned short btile[64][64];
    __shared__ __align__(16) float etile[64][65];

    const int tid  = threadIdx.x;
    const int lane = tid & 63;
    const int wid  = tid >> 6;
    const int wm   = (wid >> 1) * 32;
    const int wn   = (wid & 1) * 32;
    const int m0   = blockIdx.x * 64;
    const int n0   = blockIdx.y * 64;

    f32x4 acc[2][2];
    #pragma unroll
    for (int i = 0; i < 2; ++i)
        #pragma unroll
        for (int j = 0; j < 2; ++j) acc[i][j] = (f32x4){0.f, 0.f, 0.f, 0.f};

    for (int k0 = 0; k0 < DIM; k0 += 64) {
        #pragma unroll
        for (int r = 0; r < 4; ++r) {
            int c   = tid + r * 256;
            int row = c >> 4;
            int ko  = (c & 15) << 2;
            float4 va = *(const float4*)(x + (size_t)(m0 + row) * DIM + k0 + ko);
            float4 vb = *(const float4*)(w + (size_t)(n0 + row) * DIM + k0 + ko);
            union { unsigned short us[4]; uint2 u2; } pa, pb;
            pa.us[0] = f2bf(va.x); pa.us[1] = f2bf(va.y);
            pa.us[2] = f2bf(va.z); pa.us[3] = f2bf(va.w);
            pb.us[0] = f2bf(vb.x); pb.us[1] = f2bf(vb.y);
            pb.us[2] = f2bf(vb.z); pb.us[3] = f2bf(vb.w);
            *(uint2*)&atile[row][ko] = pa.u2;
            *(uint2*)&btile[row][ko] = pb.u2;
        }
        __syncthreads();
        #pragma unroll
        for (int kk = 0; kk < 2; ++kk) {
            bf16x8 af[2], bfr[2];
            #pragma unroll
            for (int i = 0; i < 2; ++i)
                af[i] = *(const bf16x8*)&atile[wm + i*16 + (lane & 15)][kk*32 + (lane >> 4)*8];
            #pragma unroll
            for (int j = 0; j < 2; ++j)
                bfr[j] = *(const bf16x8*)&btile[wn + j*16 + (lane & 15)][kk*32 + (lane >> 4)*8];
            #pragma unroll
            for (int i = 0; i < 2; ++i)
                #pragma unroll
                for (int j = 0; j < 2; ++j)
                    acc[i][j] = __builtin_amdgcn_mfma_f32_16x16x32_bf16(af[i], bfr[j], acc[i][j], 0, 0, 0);
        }
        __syncthreads();
    }

    // epilogue: acc + bias -> etile (fp32)
    #pragma unroll
    for (int i = 0; i < 2; ++i)
        #pragma unroll
        for (int j = 0; j < 2; ++j)
            #pragma unroll
            for (int v = 0; v < 4; ++v) {
                int row = wm + i*16 + (lane >> 4)*4 + v;
                int col = wn + j*16 + (lane & 15);
                etile[row][col] = acc[i][j][v] + bias[n0 + col];
            }
    __syncthreads();

    const int sect = n0 >> 10;          // 0=q, 1=k, 2=v
    const int h    = (n0 & 1023) >> 6;  // head index (tile is head-aligned)

    if (sect < 2) {
        unsigned short* dst = (sect == 0) ? qb : kb;
        const float sc = (sect == 0) ? 0.125f : 1.0f;   // fold softmax scale into q
        #pragma unroll
        for (int it = 0; it < 8; ++it) {
            int row = (tid >> 5) + it * 8;
            int d0  = (tid & 31) * 2;
            int gm  = m0 + row;
            int bb  = gm >> 11;
            int n   = gm & 2047;
            float c0 = rcos[n*64 + d0], c1 = rcos[n*64 + d0 + 1];
            float s0 = rsin[n*64 + d0], s1 = rsin[n*64 + d0 + 1];
            float q0 = etile[row][d0], q1 = etile[row][d0 + 1];
            bool lo = (d0 < 32);
            float r0 = lo ? -etile[row][d0 + 32] : etile[row][d0 - 32];
            float r1 = lo ? -etile[row][d0 + 33] : etile[row][d0 - 31];
            union { unsigned short us[2]; unsigned int u; } pk;
            pk.us[0] = f2bf((q0 * c0 + r0 * s0) * sc);
            pk.us[1] = f2bf((q1 * c1 + r1 * s1) * sc);
            *(unsigned int*)(dst + (((size_t)(bb*NUM_HEADS + h) * NTOK + n) << 6) + d0) = pk.u;
        }
    } else {
        #pragma unroll
        for (int it = 0; it < 8; ++it) {
            int d  = (tid >> 5) + it * 8;
            int nl = (tid & 31) * 2;
            int gm = m0 + nl;
            int bb = gm >> 11;
            int n  = gm & 2047;
            union { unsigned short us[2]; unsigned int u; } pk;
            pk.us[0] = f2bf(etile[nl][d]);
            pk.us[1] = f2bf(etile[nl + 1][d]);
            *(unsigned int*)(vtb + ((size_t)(bb*NUM_HEADS + h) * HEAD_DIM + d) * NTOK + n) = pk.u;
        }
    }
}

// ---------------- Kernel 2: flash attention ----------------
// grid: (N/64 q-tiles, B*H). block: 256 (4 waves x 16 q-rows).
__global__ __launch_bounds__(256) void k_attn(
    const unsigned short* __restrict__ qb, const unsigned short* __restrict__ kb,
    const unsigned short* __restrict__ vtb, unsigned short* __restrict__ attnb)
{
    __shared__ __align__(16) unsigned short ktile[64][64];
    __shared__ __align__(16) unsigned short vtile[64][64];
    __shared__ __align__(16) unsigned short ptile[4][16][64];

    const int tid  = threadIdx.x;
    const int lane = tid & 63;
    const int w    = tid >> 6;
    const int q0   = blockIdx.x * 64;
    const int bh   = blockIdx.y;
    const int b    = bh >> 4, h = bh & 15;

    bf16x8 qa[2];
    {
        const size_t qrow = ((size_t)bh * NTOK + q0 + w * 16 + (lane & 15)) * 64;
        #pragma unroll
        for (int kk = 0; kk < 2; ++kk)
            qa[kk] = *(const bf16x8*)(qb + qrow + kk*32 + (lane >> 4)*8);
    }

    f32x4 o[4];
    #pragma unroll
    for (int fn = 0; fn < 4; ++fn) o[fn] = (f32x4){0.f, 0.f, 0.f, 0.f};
    float mrow[4] = {-1e30f, -1e30f, -1e30f, -1e30f};
    float lrow[4] = {0.f, 0.f, 0.f, 0.f};

    for (int kv0 = 0; kv0 < NTOK; kv0 += 64) {
        #pragma unroll
        for (int r = 0; r < 2; ++r) {
            int c   = tid + r * 256;
            int row = c >> 3;
            int off = (c & 7) * 8;
            *(uint4*)&ktile[row][off] =
                *(const uint4*)(kb + ((size_t)bh*NTOK + kv0 + row) * 64 + off);
            *(uint4*)&vtile[row][off] =
                *(const uint4*)(vtb + ((size_t)bh*HEAD_DIM + row) * NTOK + kv0 + off);
        }
        __syncthreads();

        f32x4 s[4];
        #pragma unroll
        for (int fn = 0; fn < 4; ++fn) s[fn] = (f32x4){0.f, 0.f, 0.f, 0.f};
        #pragma unroll
        for (int kk = 0; kk < 2; ++kk) {
            #pragma unroll
            for (int fn = 0; fn < 4; ++fn) {
                bf16x8 kf = *(const bf16x8*)&ktile[fn*16 + (lane & 15)][kk*32 + (lane >> 4)*8];
                s[fn] = __builtin_amdgcn_mfma_f32_16x16x32_bf16(qa[kk], kf, s[fn], 0, 0, 0);
            }
        }

        // online softmax (rows r = 4*(lane>>4)+v, 16 lanes per row-group)
        float scl[4];
        #pragma unroll
        for (int v = 0; v < 4; ++v) {
            float mx = fmaxf(fmaxf(s[0][v], s[1][v]), fmaxf(s[2][v], s[3][v]));
            mx = fmaxf(mx, __shfl_xor(mx, 1));
            mx = fmaxf(mx, __shfl_xor(mx, 2));
            mx = fmaxf(mx, __shfl_xor(mx, 4));
            mx = fmaxf(mx, __shfl_xor(mx, 8));
            float mnew = fmaxf(mrow[v], mx);
            scl[v] = __expf(mrow[v] - mnew);
            mrow[v] = mnew;
        }
        float rs[4] = {0.f, 0.f, 0.f, 0.f};
        #pragma unroll
        for (int fn = 0; fn < 4; ++fn)
            #pragma unroll
            for (int v = 0; v < 4; ++v) {
                float p = __expf(s[fn][v] - mrow[v]);
                s[fn][v] = p;
                rs[v] += p;
            }
        #pragma unroll
        for (int v = 0; v < 4; ++v) {
            rs[v] += __shfl_xor(rs[v], 1);
            rs[v] += __shfl_xor(rs[v], 2);
            rs[v] += __shfl_xor(rs[v], 4);
            rs[v] += __shfl_xor(rs[v], 8);
            lrow[v] = lrow[v] * scl[v] + rs[v];
        }
        #pragma unroll
        for (int fn = 0; fn < 4; ++fn)
            #pragma unroll
            for (int v = 0; v < 4; ++v)
                o[fn][v] *= scl[v];

        // P (D-layout) -> LDS -> A-layout
        #pragma unroll
        for (int fn = 0; fn < 4; ++fn)
            #pragma unroll
            for (int v = 0; v < 4; ++v)
                ptile[w][(lane >> 4)*4 + v][fn*16 + (lane & 15)] = f2bf(s[fn][v]);
        __syncthreads();

        #pragma unroll
        for (int kk = 0; kk < 2; ++kk) {
            bf16x8 pa = *(const bf16x8*)&ptile[w][lane & 15][kk*32 + (lane >> 4)*8];
            #pragma unroll
            for (int fn = 0; fn < 4; ++fn) {
                bf16x8 vf = *(const bf16x8*)&vtile[fn*16 + (lane & 15)][kk*32 + (lane >> 4)*8];
                o[fn] = __builtin_amdgcn_mfma_f32_16x16x32_bf16(pa, vf, o[fn], 0, 0, 0);
            }
        }
        __syncthreads();
    }

    #pragma unroll
    for (int fn = 0; fn < 4; ++fn)
        #pragma unroll
        for (int v = 0; v < 4; ++v) {
            int rl = w*16 + (lane >> 4)*4 + v;
            int n  = q0 + rl;
            float val = o[fn][v] / lrow[v];
            attnb[((size_t)(b*NTOK + n)) * DIM + h*HEAD_DIM + fn*16 + (lane & 15)] = f2bf(val);
        }
}

// ---------------- Kernel 3: output projection ----------------
__global__ __launch_bounds__(256) void k_proj(
    const unsigned short* __restrict__ a, const float* __restrict__ w,
    const float* __restrict__ bias, float* __restrict__ out)
{
    __shared__ __align__(16) unsigned short atile[64][64];
    __shared__ __align__(16) unsigned short btile[64][64];

    const int tid  = threadIdx.x;
    const int lane = tid & 63;
    const int wid  = tid >> 6;
    const int wm   = (wid >> 1) * 32;
    const int wn   = (wid & 1) * 32;
    const int m0   = blockIdx.x * 64;
    const int n0   = blockIdx.y * 64;

    f32x4 acc[2][2];
    #pragma unroll
    for (int i = 0; i < 2; ++i)
        #pragma unroll
        for (int j = 0; j < 2; ++j) acc[i][j] = (f32x4){0.f, 0.f, 0.f, 0.f};

    for (int k0 = 0; k0 < DIM; k0 += 64) {
        #pragma unroll
        for (int r = 0; r < 2; ++r) {
            int c   = tid + r * 256;
            int row = c >> 3;
            int off = (c & 7) * 8;
            *(uint4*)&atile[row][off] =
                *(const uint4*)(a + (size_t)(m0 + row) * DIM + k0 + off);
        }
        #pragma unroll
        for (int r = 0; r < 4; ++r) {
            int c   = tid + r * 256;
            int row = c >> 4;
            int ko  = (c & 15) << 2;
            float4 vb = *(const float4*)(w + (size_t)(n0 + row) * DIM + k0 + ko);
            union { unsigned short us[4]; uint2 u2; } pb;
            pb.us[0] = f2bf(vb.x); pb.us[1] = f2bf(vb.y);
            pb.us[2] = f2bf(vb.z); pb.us[3] = f2bf(vb.w);
            *(uint2*)&btile[row][ko] = pb.u2;
        }
        __syncthreads();
        #pragma unroll
        for (int kk = 0; kk < 2; ++kk) {
            bf16x8 af[2], bfr[2];
            #pragma unroll
            for (int i = 0; i < 2; ++i)
                af[i] = *(const bf16x8*)&atile[wm + i*16 + (lane & 15)][kk*32 + (lane >> 4)*8];
            #pragma unroll
            for (int j = 0; j < 2; ++j)
                bfr[j] = *(const bf16x8*)&btile[wn + j*16 + (lane & 15)][kk*32 + (lane >> 4)*8];
            #pragma unroll
            for (int i = 0; i < 2; ++i)
                #pragma unroll
                for (int j = 0; j < 2; ++j)
                    acc[i][j] = __builtin_amdgcn_mfma_f32_16x16x32_bf16(af[i], bfr[j], acc[i][j], 0, 0, 0);
        }
        __syncthreads();
    }

    #pragma unroll
    for (int i = 0; i < 2; ++i)
        #pragma unroll
        for (int j = 0; j < 2; ++j)
            #pragma unroll
            for (int v = 0; v < 4; ++v) {
                int row = m0 + wm + i*16 + (lane >> 4)*4 + v;
                int col = n0 + wn + j*16 + (lane & 15);
                out[(size_t)row * DIM + col] = acc[i][j][v] + bias[col];
            }
}

extern "C" void kernel_launch(void* const* d_in, const int* in_sizes, int n_in,
                              void* d_out, int out_size, void* d_ws, size_t ws_size,
                              hipStream_t stream)
{
    const float* x      = (const float*)d_in[0];
    const float* rcos   = (const float*)d_in[1];
    const float* rsin   = (const float*)d_in[2];
    const float* qkv_w  = (const float*)d_in[3];
    const float* qkv_b  = (const float*)d_in[4];
    const float* proj_w = (const float*)d_in[5];
    const float* proj_b = (const float*)d_in[6];
    float* out = (float*)d_out;

    const size_t BUF = (size_t)2 * NUM_HEADS * NTOK * HEAD_DIM;  // 4,194,304 elems
    unsigned short* qb    = (unsigned short*)d_ws;
    unsigned short* kb    = qb + BUF;
    unsigned short* vtb   = kb + BUF;
    unsigned short* attnb = vtb + BUF;

    k_qkv_rope<<<dim3(64, 48), 256, 0, stream>>>(x, qkv_w, qkv_b, rcos, rsin, qb, kb, vtb);
    k_attn<<<dim3(32, 32), 256, 0, stream>>>(qb, kb, vtb, attnb);
    k_proj<<<dim3(64, 16), 256, 0, stream>>>(attnb, proj_w, proj_b, out);
}

// Round 2
// 238.545 us; speedup vs baseline: 1.4487x; 1.4487x over previous
//
#include <hip/hip_runtime.h>

#define NUM_HEADS 16
#define HEAD_DIM 64
#define DIM 1024
#define NTOK 2048
#define MTOT 4096

typedef __attribute__((ext_vector_type(8))) short bf16x8;
typedef __attribute__((ext_vector_type(4))) float f32x4;

__device__ __forceinline__ unsigned short f2bf(float f) {
    union { float f; unsigned int u; } v; v.f = f;
    unsigned int r = v.u + 0x7FFFu + ((v.u >> 16) & 1u);
    return (unsigned short)(r >> 16);
}

__device__ __forceinline__ void gload16(const unsigned short* g, unsigned short* l) {
    __builtin_amdgcn_global_load_lds(
        (const __attribute__((address_space(1))) void*)g,
        (__attribute__((address_space(3))) void*)l, 16, 0, 0);
}

// ---------------- Kernel 0: fp32 -> bf16 convert (8 elems/thread) ----------------
__global__ __launch_bounds__(256) void k_conv(const float* __restrict__ src,
                                              unsigned short* __restrict__ dst, int n)
{
    int i = (blockIdx.x * 256 + threadIdx.x) * 8;
    if (i >= n) return;
    float4 a = *(const float4*)(src + i);
    float4 b = *(const float4*)(src + i + 4);
    union { unsigned short us[8]; uint4 u4; } p;
    p.us[0] = f2bf(a.x); p.us[1] = f2bf(a.y); p.us[2] = f2bf(a.z); p.us[3] = f2bf(a.w);
    p.us[4] = f2bf(b.x); p.us[5] = f2bf(b.y); p.us[6] = f2bf(b.z); p.us[7] = f2bf(b.w);
    *(uint4*)(dst + i) = p.u4;
}

// ---------------- Kernel 1: QKV GEMM (bf16 in) + bias + RoPE + layout ----------------
// 128x128 tile, BK=64, global_load_lds staging. 4 waves, each 64x64 output.
// q,k -> [b,h][n][d] bf16 (q scaled by 0.125); v -> [b,h][d][n] bf16 (transposed)
__global__ __launch_bounds__(256) void k_gemm_qkv(
    const unsigned short* __restrict__ xb, const unsigned short* __restrict__ wb,
    const float* __restrict__ bias, const float* __restrict__ rcos,
    const float* __restrict__ rsin,
    unsigned short* __restrict__ qb, unsigned short* __restrict__ kb,
    unsigned short* __restrict__ vtb)
{
    __shared__ __align__(16) unsigned char smem[34816];   // As(16K)+Bs(16K), vt(34K) union
    unsigned short (*As)[64] = (unsigned short (*)[64])smem;
    unsigned short (*Bs)[64] = (unsigned short (*)[64])(smem + 16384);

    const int tid  = threadIdx.x;
    const int lane = tid & 63;
    const int wid  = tid >> 6;
    const int wm   = (wid >> 1) * 64;
    const int wn   = (wid & 1) * 64;
    const int m0   = blockIdx.x * 128;
    const int n0   = blockIdx.y * 128;

    const int lrow = lane >> 3;
    const int lcol = (lane & 7) * 8;

    f32x4 acc[4][4];
    #pragma unroll
    for (int i = 0; i < 4; ++i)
        #pragma unroll
        for (int j = 0; j < 4; ++j) acc[i][j] = (f32x4){0.f, 0.f, 0.f, 0.f};

    for (int k0 = 0; k0 < DIM; k0 += 64) {
        #pragma unroll
        for (int it = 0; it < 4; ++it) {
            int row = (wid * 4 + it) * 8 + lrow;   // 0..127
            gload16(xb + (size_t)(m0 + row) * DIM + k0 + lcol, &As[row][lcol]);
            gload16(wb + (size_t)(n0 + row) * DIM + k0 + lcol, &Bs[row][lcol]);
        }
        __syncthreads();
        #pragma unroll
        for (int kk = 0; kk < 2; ++kk) {
            bf16x8 af[4], bfr[4];
            #pragma unroll
            for (int i = 0; i < 4; ++i)
                af[i] = *(const bf16x8*)&As[wm + i*16 + (lane & 15)][kk*32 + (lane >> 4)*8];
            #pragma unroll
            for (int j = 0; j < 4; ++j)
                bfr[j] = *(const bf16x8*)&Bs[wn + j*16 + (lane & 15)][kk*32 + (lane >> 4)*8];
            #pragma unroll
            for (int i = 0; i < 4; ++i)
                #pragma unroll
                for (int j = 0; j < 4; ++j)
                    acc[i][j] = __builtin_amdgcn_mfma_f32_16x16x32_bf16(af[i], bfr[j], acc[i][j], 0, 0, 0);
        }
        __syncthreads();
    }

    const int sect = n0 >> 10;                 // 0=q, 1=k, 2=v
    float bq[4];
    #pragma unroll
    for (int j = 0; j < 4; ++j) bq[j] = bias[n0 + wn + j*16 + (lane & 15)];

    if (sect < 2) {
        // RoPE in registers: partner of fragment j is j^2 (d +/- 32), same lane.
        unsigned short* dst = sect ? kb : qb;
        const float sc = sect ? 1.0f : 0.125f;
        const int h = ((n0 & 1023) + wn) >> 6;
        #pragma unroll
        for (int i = 0; i < 4; ++i) {
            #pragma unroll
            for (int v = 0; v < 4; ++v) {
                int gm = m0 + wm + i*16 + (lane >> 4)*4 + v;
                int b  = gm >> 11, n = gm & 2047;
                size_t base = ((size_t)(b*NUM_HEADS + h) * NTOK + n) << 6;
                #pragma unroll
                for (int j = 0; j < 4; ++j) {
                    int d = j*16 + (lane & 15);
                    float val = acc[i][j][v] + bq[j];
                    float vp  = acc[i][j^2][v] + bq[j^2];
                    float rot = (j < 2) ? -vp : vp;
                    float c = rcos[n*64 + d], s = rsin[n*64 + d];
                    dst[base + d] = f2bf((val * c + rot * s) * sc);
                }
            }
        }
    } else {
        // v: bias + transpose via LDS (vt[d_tile][n_tile]), coalesced writes along n
        unsigned short (*vt)[136] = (unsigned short (*)[136])smem;
        #pragma unroll
        for (int i = 0; i < 4; ++i)
            #pragma unroll
            for (int j = 0; j < 4; ++j)
                #pragma unroll
                for (int v = 0; v < 4; ++v) {
                    int row = wm + i*16 + (lane >> 4)*4 + v;
                    int c   = wn + j*16 + (lane & 15);
                    vt[c][row] = f2bf(acc[i][j][v] + bq[j]);
                }
        __syncthreads();
        const int b = m0 >> 11;            // tile never spans batch boundary
        const int nbase = m0 & 2047;
        #pragma unroll
        for (int it = 0; it < 8; ++it) {
            int c   = (tid >> 4) + it * 16;
            int sc2 = (n0 & 1023) + c;
            int hh  = sc2 >> 6, d = sc2 & 63;
            int nloc = (tid & 15) * 8;
            uint4 val = *(uint4*)&vt[c][nloc];
            *(uint4*)(vtb + ((size_t)(b*NUM_HEADS + hh) * HEAD_DIM + d) * NTOK + nbase + nloc) = val;
        }
    }
}

// ---------------- Kernel 2: flash attention (unchanged this round) ----------------
__global__ __launch_bounds__(256) void k_attn(
    const unsigned short* __restrict__ qb, const unsigned short* __restrict__ kb,
    const unsigned short* __restrict__ vtb, unsigned short* __restrict__ attnb)
{
    __shared__ __align__(16) unsigned short ktile[64][64];
    __shared__ __align__(16) unsigned short vtile[64][64];
    __shared__ __align__(16) unsigned short ptile[4][16][64];

    const int tid  = threadIdx.x;
    const int lane = tid & 63;
    const int w    = tid >> 6;
    const int q0   = blockIdx.x * 64;
    const int bh   = blockIdx.y;
    const int b    = bh >> 4, h = bh & 15;

    bf16x8 qa[2];
    {
        const size_t qrow = ((size_t)bh * NTOK + q0 + w * 16 + (lane & 15)) * 64;
        #pragma unroll
        for (int kk = 0; kk < 2; ++kk)
            qa[kk] = *(const bf16x8*)(qb + qrow + kk*32 + (lane >> 4)*8);
    }

    f32x4 o[4];
    #pragma unroll
    for (int fn = 0; fn < 4; ++fn) o[fn] = (f32x4){0.f, 0.f, 0.f, 0.f};
    float mrow[4] = {-1e30f, -1e30f, -1e30f, -1e30f};
    float lrow[4] = {0.f, 0.f, 0.f, 0.f};

    for (int kv0 = 0; kv0 < NTOK; kv0 += 64) {
        #pragma unroll
        for (int r = 0; r < 2; ++r) {
            int c   = tid + r * 256;
            int row = c >> 3;
            int off = (c & 7) * 8;
            *(uint4*)&ktile[row][off] =
                *(const uint4*)(kb + ((size_t)bh*NTOK + kv0 + row) * 64 + off);
            *(uint4*)&vtile[row][off] =
                *(const uint4*)(vtb + ((size_t)bh*HEAD_DIM + row) * NTOK + kv0 + off);
        }
        __syncthreads();

        f32x4 s[4];
        #pragma unroll
        for (int fn = 0; fn < 4; ++fn) s[fn] = (f32x4){0.f, 0.f, 0.f, 0.f};
        #pragma unroll
        for (int kk = 0; kk < 2; ++kk) {
            #pragma unroll
            for (int fn = 0; fn < 4; ++fn) {
                bf16x8 kf = *(const bf16x8*)&ktile[fn*16 + (lane & 15)][kk*32 + (lane >> 4)*8];
                s[fn] = __builtin_amdgcn_mfma_f32_16x16x32_bf16(qa[kk], kf, s[fn], 0, 0, 0);
            }
        }

        float scl[4];
        #pragma unroll
        for (int v = 0; v < 4; ++v) {
            float mx = fmaxf(fmaxf(s[0][v], s[1][v]), fmaxf(s[2][v], s[3][v]));
            mx = fmaxf(mx, __shfl_xor(mx, 1));
            mx = fmaxf(mx, __shfl_xor(mx, 2));
            mx = fmaxf(mx, __shfl_xor(mx, 4));
            mx = fmaxf(mx, __shfl_xor(mx, 8));
            float mnew = fmaxf(mrow[v], mx);
            scl[v] = __expf(mrow[v] - mnew);
            mrow[v] = mnew;
        }
        float rs[4] = {0.f, 0.f, 0.f, 0.f};
        #pragma unroll
        for (int fn = 0; fn < 4; ++fn)
            #pragma unroll
            for (int v = 0; v < 4; ++v) {
                float p = __expf(s[fn][v] - mrow[v]);
                s[fn][v] = p;
                rs[v] += p;
            }
        #pragma unroll
        for (int v = 0; v < 4; ++v) {
            rs[v] += __shfl_xor(rs[v], 1);
            rs[v] += __shfl_xor(rs[v], 2);
            rs[v] += __shfl_xor(rs[v], 4);
            rs[v] += __shfl_xor(rs[v], 8);
            lrow[v] = lrow[v] * scl[v] + rs[v];
        }
        #pragma unroll
        for (int fn = 0; fn < 4; ++fn)
            #pragma unroll
            for (int v = 0; v < 4; ++v)
                o[fn][v] *= scl[v];

        #pragma unroll
        for (int fn = 0; fn < 4; ++fn)
            #pragma unroll
            for (int v = 0; v < 4; ++v)
                ptile[w][(lane >> 4)*4 + v][fn*16 + (lane & 15)] = f2bf(s[fn][v]);
        __syncthreads();

        #pragma unroll
        for (int kk = 0; kk < 2; ++kk) {
            bf16x8 pa = *(const bf16x8*)&ptile[w][lane & 15][kk*32 + (lane >> 4)*8];
            #pragma unroll
            for (int fn = 0; fn < 4; ++fn) {
                bf16x8 vf = *(const bf16x8*)&vtile[fn*16 + (lane & 15)][kk*32 + (lane >> 4)*8];
                o[fn] = __builtin_amdgcn_mfma_f32_16x16x32_bf16(pa, vf, o[fn], 0, 0, 0);
            }
        }
        __syncthreads();
    }

    #pragma unroll
    for (int fn = 0; fn < 4; ++fn)
        #pragma unroll
        for (int v = 0; v < 4; ++v) {
            int rl = w*16 + (lane >> 4)*4 + v;
            int n  = q0 + rl;
            float val = o[fn][v] / lrow[v];
            attnb[((size_t)(b*NTOK + n)) * DIM + h*HEAD_DIM + fn*16 + (lane & 15)] = f2bf(val);
        }
}

// ---------------- Kernel 3: output projection (128x128 tile, bf16 in) ----------------
__global__ __launch_bounds__(256) void k_proj(
    const unsigned short* __restrict__ a, const unsigned short* __restrict__ wb,
    const float* __restrict__ bias, float* __restrict__ out)
{
    __shared__ __align__(16) unsigned short As[128][64];
    __shared__ __align__(16) unsigned short Bs[128][64];

    const int tid  = threadIdx.x;
    const int lane = tid & 63;
    const int wid  = tid >> 6;
    const int wm   = (wid >> 1) * 64;
    const int wn   = (wid & 1) * 64;
    const int m0   = blockIdx.x * 128;
    const int n0   = blockIdx.y * 128;

    const int lrow = lane >> 3;
    const int lcol = (lane & 7) * 8;

    f32x4 acc[4][4];
    #pragma unroll
    for (int i = 0; i < 4; ++i)
        #pragma unroll
        for (int j = 0; j < 4; ++j) acc[i][j] = (f32x4){0.f, 0.f, 0.f, 0.f};

    for (int k0 = 0; k0 < DIM; k0 += 64) {
        #pragma unroll
        for (int it = 0; it < 4; ++it) {
            int row = (wid * 4 + it) * 8 + lrow;
            gload16(a  + (size_t)(m0 + row) * DIM + k0 + lcol, &As[row][lcol]);
            gload16(wb + (size_t)(n0 + row) * DIM + k0 + lcol, &Bs[row][lcol]);
        }
        __syncthreads();
        #pragma unroll
        for (int kk = 0; kk < 2; ++kk) {
            bf16x8 af[4], bfr[4];
            #pragma unroll
            for (int i = 0; i < 4; ++i)
                af[i] = *(const bf16x8*)&As[wm + i*16 + (lane & 15)][kk*32 + (lane >> 4)*8];
            #pragma unroll
            for (int j = 0; j < 4; ++j)
                bfr[j] = *(const bf16x8*)&Bs[wn + j*16 + (lane & 15)][kk*32 + (lane >> 4)*8];
            #pragma unroll
            for (int i = 0; i < 4; ++i)
                #pragma unroll
                for (int j = 0; j < 4; ++j)
                    acc[i][j] = __builtin_amdgcn_mfma_f32_16x16x32_bf16(af[i], bfr[j], acc[i][j], 0, 0, 0);
        }
        __syncthreads();
    }

    #pragma unroll
    for (int i = 0; i < 4; ++i)
        #pragma unroll
        for (int j = 0; j < 4; ++j)
            #pragma unroll
            for (int v = 0; v < 4; ++v) {
                int row = m0 + wm + i*16 + (lane >> 4)*4 + v;
                int col = n0 + wn + j*16 + (lane & 15);
                out[(size_t)row * DIM + col] = acc[i][j][v] + bias[col];
            }
}

extern "C" void kernel_launch(void* const* d_in, const int* in_sizes, int n_in,
                              void* d_out, int out_size, void* d_ws, size_t ws_size,
                              hipStream_t stream)
{
    const float* x      = (const float*)d_in[0];
    const float* rcos   = (const float*)d_in[1];
    const float* rsin   = (const float*)d_in[2];
    const float* qkv_w  = (const float*)d_in[3];
    const float* qkv_b  = (const float*)d_in[4];
    const float* proj_w = (const float*)d_in[5];
    const float* proj_b = (const float*)d_in[6];
    float* out = (float*)d_out;

    const size_t BUF = (size_t)2 * NUM_HEADS * NTOK * HEAD_DIM;  // 4,194,304 elems
    unsigned short* qb    = (unsigned short*)d_ws;
    unsigned short* kb    = qb + BUF;
    unsigned short* vtb   = kb + BUF;
    unsigned short* attnb = vtb + BUF;
    unsigned short* xbf   = attnb + BUF;                 // 4096*1024
    unsigned short* wqkvb = xbf + (size_t)MTOT * DIM;    // 3072*1024
    unsigned short* wprjb = wqkvb + (size_t)3 * DIM * DIM; // 1024*1024

    k_conv<<<dim3((MTOT*DIM)/2048), 256, 0, stream>>>(x, xbf, MTOT*DIM);
    k_conv<<<dim3((3*DIM*DIM)/2048), 256, 0, stream>>>(qkv_w, wqkvb, 3*DIM*DIM);
    k_conv<<<dim3((DIM*DIM)/2048), 256, 0, stream>>>(proj_w, wprjb, DIM*DIM);

    k_gemm_qkv<<<dim3(32, 24), 256, 0, stream>>>(xbf, wqkvb, qkv_b, rcos, rsin, qb, kb, vtb);
    k_attn<<<dim3(32, 32), 256, 0, stream>>>(qb, kb, vtb, attnb);
    k_proj<<<dim3(32, 8), 256, 0, stream>>>(attnb, wprjb, proj_b, out);
}

// Round 3
// 170.005 us; speedup vs baseline: 2.0328x; 1.4032x over previous
//
#include <hip/hip_runtime.h>

#define NUM_HEADS 16
#define HEAD_DIM 64
#define DIM 1024
#define NTOK 2048
#define MTOT 4096

typedef __attribute__((ext_vector_type(8))) short bf16x8;
typedef __attribute__((ext_vector_type(4))) float f32x4;

__device__ __forceinline__ unsigned short f2bf(float f) {
    union { float f; unsigned int u; } v; v.f = f;
    unsigned int r = v.u + 0x7FFFu + ((v.u >> 16) & 1u);
    return (unsigned short)(r >> 16);
}

__device__ __forceinline__ void gload16(const unsigned short* g, unsigned short* l) {
    __builtin_amdgcn_global_load_lds(
        (const __attribute__((address_space(1))) void*)g,
        (__attribute__((address_space(3))) void*)l, 16, 0, 0);
}

// ---------------- Kernel 0: fp32 -> bf16 convert ----------------
__global__ __launch_bounds__(256) void k_conv(const float* __restrict__ src,
                                              unsigned short* __restrict__ dst, int n)
{
    int i = (blockIdx.x * 256 + threadIdx.x) * 8;
    if (i >= n) return;
    float4 a = *(const float4*)(src + i);
    float4 b = *(const float4*)(src + i + 4);
    union { unsigned short us[8]; uint4 u4; } p;
    p.us[0] = f2bf(a.x); p.us[1] = f2bf(a.y); p.us[2] = f2bf(a.z); p.us[3] = f2bf(a.w);
    p.us[4] = f2bf(b.x); p.us[5] = f2bf(b.y); p.us[6] = f2bf(b.z); p.us[7] = f2bf(b.w);
    *(uint4*)(dst + i) = p.u4;
}

// ---------------- Kernel 1: QKV GEMM + bias + RoPE + layout ----------------
// 128x128 tile, BK=64, swizzled LDS (chunk c -> c^(row&7) per 128B row).
// Staging: linear LDS dest + inverse-swizzled global source (rule 21).
__global__ __launch_bounds__(256) void k_gemm_qkv(
    const unsigned short* __restrict__ xb, const unsigned short* __restrict__ wb,
    const float* __restrict__ bias, const float* __restrict__ rcos,
    const float* __restrict__ rsin,
    unsigned short* __restrict__ qb, unsigned short* __restrict__ kb,
    unsigned short* __restrict__ vtb)
{
    __shared__ __align__(16) unsigned char smem[34816];
    unsigned short* As = (unsigned short*)smem;            // [128][64] swizzled
    unsigned short* Bs = (unsigned short*)(smem + 16384);

    const int tid  = threadIdx.x;
    const int lane = tid & 63;
    const int wid  = tid >> 6;
    const int lr   = lane & 15;
    const int g    = lane >> 4;
    const int wm   = (wid >> 1) * 64;
    const int wn   = (wid & 1) * 64;
    const int m0   = blockIdx.x * 128;
    const int n0   = blockIdx.y * 128;

    f32x4 acc[4][4];
    #pragma unroll
    for (int i = 0; i < 4; ++i)
        #pragma unroll
        for (int j = 0; j < 4; ++j) acc[i][j] = (f32x4){0.f, 0.f, 0.f, 0.f};

    for (int k0 = 0; k0 < DIM; k0 += 64) {
        #pragma unroll
        for (int it = 0; it < 4; ++it) {
            int p   = tid + it * 256;
            int row = p >> 3;
            int c   = (p & 7) ^ (row & 7);
            gload16(xb + (size_t)(m0 + row) * DIM + k0 + c*8, As + p*8);
            gload16(wb + (size_t)(n0 + row) * DIM + k0 + c*8, Bs + p*8);
        }
        __syncthreads();
        #pragma unroll
        for (int kk = 0; kk < 2; ++kk) {
            bf16x8 af[4], bfr[4];
            #pragma unroll
            for (int i = 0; i < 4; ++i) {
                int row = wm + i*16 + lr;
                af[i] = *(const bf16x8*)(As + row*64 + (((kk*4 + g) ^ (row & 7)) << 3));
            }
            #pragma unroll
            for (int j = 0; j < 4; ++j) {
                int row = wn + j*16 + lr;
                bfr[j] = *(const bf16x8*)(Bs + row*64 + (((kk*4 + g) ^ (row & 7)) << 3));
            }
            #pragma unroll
            for (int i = 0; i < 4; ++i)
                #pragma unroll
                for (int j = 0; j < 4; ++j)
                    acc[i][j] = __builtin_amdgcn_mfma_f32_16x16x32_bf16(af[i], bfr[j], acc[i][j], 0, 0, 0);
        }
        __syncthreads();
    }

    const int sect = n0 >> 10;                 // 0=q, 1=k, 2=v
    float bq[4];
    #pragma unroll
    for (int j = 0; j < 4; ++j) bq[j] = bias[n0 + wn + j*16 + lr];

    if (sect < 2) {
        unsigned short* dst = sect ? kb : qb;
        const float sc = sect ? 1.0f : 0.125f;   // softmax scale folded into q
        const int h = ((n0 & 1023) + wn) >> 6;
        #pragma unroll
        for (int i = 0; i < 4; ++i) {
            #pragma unroll
            for (int v = 0; v < 4; ++v) {
                int gm = m0 + wm + i*16 + g*4 + v;
                int b  = gm >> 11, n = gm & 2047;
                size_t base = ((size_t)(b*NUM_HEADS + h) * NTOK + n) << 6;
                #pragma unroll
                for (int j = 0; j < 4; ++j) {
                    int d = j*16 + lr;
                    float val = acc[i][j][v] + bq[j];
                    float vp  = acc[i][j^2][v] + bq[j^2];
                    float rot = (j < 2) ? -vp : vp;
                    float c = rcos[n*64 + d], s = rsin[n*64 + d];
                    dst[base + d] = f2bf((val * c + rot * s) * sc);
                }
            }
        }
    } else {
        unsigned short (*vt)[136] = (unsigned short (*)[136])smem;
        __syncthreads();
        #pragma unroll
        for (int i = 0; i < 4; ++i)
            #pragma unroll
            for (int j = 0; j < 4; ++j)
                #pragma unroll
                for (int v = 0; v < 4; ++v) {
                    int row = wm + i*16 + g*4 + v;
                    int c   = wn + j*16 + lr;
                    vt[c][row] = f2bf(acc[i][j][v] + bq[j]);
                }
        __syncthreads();
        const int b = m0 >> 11;
        const int nbase = m0 & 2047;
        #pragma unroll
        for (int it = 0; it < 8; ++it) {
            int c   = (tid >> 4) + it * 16;
            int sc2 = (n0 & 1023) + c;
            int hh  = sc2 >> 6, d = sc2 & 63;
            int nloc = (tid & 15) * 8;
            uint4 val = *(uint4*)&vt[c][nloc];
            *(uint4*)(vtb + ((size_t)(b*NUM_HEADS + hh) * HEAD_DIM + d) * NTOK + nbase + nloc) = val;
        }
    }
}

// ---------------- Kernel 2: flash attention ----------------
// 128 q-rows/block, 4 waves x 32 rows. KV tiles of 64, double-buffered,
// swizzled LDS, 1 barrier/iter. P routed through wave-private swizzled pbuf.
__global__ __launch_bounds__(256) void k_attn(
    const unsigned short* __restrict__ qb, const unsigned short* __restrict__ kb,
    const unsigned short* __restrict__ vtb, unsigned short* __restrict__ attnb)
{
    __shared__ __align__(16) unsigned short kbuf[2][4096];
    __shared__ __align__(16) unsigned short vbuf[2][4096];
    __shared__ __align__(16) unsigned short pbuf[4][2048];

    const int tid  = threadIdx.x;
    const int lane = tid & 63;
    const int w    = tid >> 6;
    const int g    = lane >> 4;
    const int lr   = lane & 15;
    const int q0   = blockIdx.x * 128;
    const int bh   = blockIdx.y;
    const int b    = bh >> 4, h = bh & 15;

    const unsigned short* kbase = kb  + (size_t)bh * NTOK * 64;
    const unsigned short* vbase = vtb + (size_t)bh * HEAD_DIM * NTOK;

    bf16x8 qa[2][2];
    #pragma unroll
    for (int i = 0; i < 2; ++i) {
        size_t qrow = ((size_t)bh * NTOK + q0 + w*32 + i*16 + lr) * 64;
        #pragma unroll
        for (int kk = 0; kk < 2; ++kk)
            qa[i][kk] = *(const bf16x8*)(qb + qrow + kk*32 + g*8);
    }

    f32x4 o[2][4];
    float m_[2][4], lsum[2][4];
    #pragma unroll
    for (int i = 0; i < 2; ++i)
        #pragma unroll
        for (int fd = 0; fd < 4; ++fd) o[i][fd] = (f32x4){0.f, 0.f, 0.f, 0.f};
    #pragma unroll
    for (int i = 0; i < 2; ++i)
        #pragma unroll
        for (int v = 0; v < 4; ++v) { m_[i][v] = -1e30f; lsum[i][v] = 0.f; }

    // stage tile 0
    #pragma unroll
    for (int hp = 0; hp < 2; ++hp) {
        int p   = tid + hp * 256;
        int row = p >> 3;
        int c   = (p & 7) ^ (row & 7);
        gload16(kbase + (size_t)row*64 + c*8, &kbuf[0][p*8]);
        gload16(vbase + (size_t)row*NTOK + c*8, &vbuf[0][p*8]);
    }
    __syncthreads();

    int cur = 0;
    for (int t = 0; t < NTOK/64; ++t) {
        if (t < NTOK/64 - 1) {
            int kvn = (t + 1) * 64;
            #pragma unroll
            for (int hp = 0; hp < 2; ++hp) {
                int p   = tid + hp * 256;
                int row = p >> 3;
                int c   = (p & 7) ^ (row & 7);
                gload16(kbase + (size_t)(kvn + row)*64 + c*8, &kbuf[cur^1][p*8]);
                gload16(vbase + (size_t)row*NTOK + kvn + c*8, &vbuf[cur^1][p*8]);
            }
        }

        // ---- QK^T ----
        f32x4 s[2][4];
        #pragma unroll
        for (int i = 0; i < 2; ++i)
            #pragma unroll
            for (int fn = 0; fn < 4; ++fn) s[i][fn] = (f32x4){0.f, 0.f, 0.f, 0.f};
        #pragma unroll
        for (int kk = 0; kk < 2; ++kk) {
            bf16x8 kf[4];
            #pragma unroll
            for (int fn = 0; fn < 4; ++fn) {
                int row = fn*16 + lr;
                kf[fn] = *(const bf16x8*)&kbuf[cur][row*64 + (((kk*4 + g) ^ (row & 7)) << 3)];
            }
            #pragma unroll
            for (int i = 0; i < 2; ++i)
                #pragma unroll
                for (int fn = 0; fn < 4; ++fn)
                    s[i][fn] = __builtin_amdgcn_mfma_f32_16x16x32_bf16(qa[i][kk], kf[fn], s[i][fn], 0, 0, 0);
        }

        // ---- online softmax: row max (group-uniform), defer-rescale ----
        float pmax[2][4];
        int need = 0;
        #pragma unroll
        for (int i = 0; i < 2; ++i)
            #pragma unroll
            for (int v = 0; v < 4; ++v) {
                float mx = fmaxf(fmaxf(s[i][0][v], s[i][1][v]), fmaxf(s[i][2][v], s[i][3][v]));
                mx = fmaxf(mx, __shfl_xor(mx, 1));
                mx = fmaxf(mx, __shfl_xor(mx, 2));
                mx = fmaxf(mx, __shfl_xor(mx, 4));
                mx = fmaxf(mx, __shfl_xor(mx, 8));
                pmax[i][v] = mx;
                need |= (mx > m_[i][v] + 8.f);
            }
        if (__any(need)) {
            #pragma unroll
            for (int i = 0; i < 2; ++i)
                #pragma unroll
                for (int v = 0; v < 4; ++v) {
                    float mn  = fmaxf(m_[i][v], pmax[i][v]);
                    float scl = __expf(m_[i][v] - mn);
                    m_[i][v]  = mn;
                    lsum[i][v] *= scl;
                    #pragma unroll
                    for (int fd = 0; fd < 4; ++fd) o[i][fd][v] *= scl;
                }
        }

        // ---- P = exp(s - m) -> wave-private swizzled pbuf ----
        unsigned short* pw = pbuf[w];
        #pragma unroll
        for (int i = 0; i < 2; ++i)
            #pragma unroll
            for (int fn = 0; fn < 4; ++fn)
                #pragma unroll
                for (int v = 0; v < 4; ++v) {
                    float p = __expf(s[i][fn][v] - m_[i][v]);
                    lsum[i][v] += p;
                    int row = i*16 + g*4 + v;
                    int col = fn*16 + lr;
                    pw[row*64 + ((((col >> 3) ^ (row & 7))) << 3) + (col & 7)] = f2bf(p);
                }

        // ---- PV ----
        #pragma unroll
        for (int kk = 0; kk < 2; ++kk) {
            bf16x8 pa[2], vf[4];
            #pragma unroll
            for (int i = 0; i < 2; ++i) {
                int row = i*16 + lr;
                pa[i] = *(const bf16x8*)&pw[row*64 + (((kk*4 + g) ^ (row & 7)) << 3)];
            }
            #pragma unroll
            for (int fd = 0; fd < 4; ++fd) {
                int row = fd*16 + lr;
                vf[fd] = *(const bf16x8*)&vbuf[cur][row*64 + (((kk*4 + g) ^ (row & 7)) << 3)];
            }
            #pragma unroll
            for (int i = 0; i < 2; ++i)
                #pragma unroll
                for (int fd = 0; fd < 4; ++fd)
                    o[i][fd] = __builtin_amdgcn_mfma_f32_16x16x32_bf16(pa[i], vf[fd], o[i][fd], 0, 0, 0);
        }
        __syncthreads();
        cur ^= 1;
    }

    // final: reduce lsum across the 16-lane group, normalize, write
    #pragma unroll
    for (int i = 0; i < 2; ++i)
        #pragma unroll
        for (int v = 0; v < 4; ++v) {
            float l = lsum[i][v];
            l += __shfl_xor(l, 1);
            l += __shfl_xor(l, 2);
            l += __shfl_xor(l, 4);
            l += __shfl_xor(l, 8);
            lsum[i][v] = 1.0f / l;
        }
    #pragma unroll
    for (int i = 0; i < 2; ++i)
        #pragma unroll
        for (int fd = 0; fd < 4; ++fd)
            #pragma unroll
            for (int v = 0; v < 4; ++v) {
                int n = q0 + w*32 + i*16 + g*4 + v;
                attnb[((size_t)(b*NTOK + n)) * DIM + h*HEAD_DIM + fd*16 + lr] =
                    f2bf(o[i][fd][v] * lsum[i][v]);
            }
}

// ---------------- Kernel 3: output projection ----------------
__global__ __launch_bounds__(256) void k_proj(
    const unsigned short* __restrict__ a, const unsigned short* __restrict__ wb,
    const float* __restrict__ bias, float* __restrict__ out)
{
    __shared__ __align__(16) unsigned short As[8192];
    __shared__ __align__(16) unsigned short Bs[8192];

    const int tid  = threadIdx.x;
    const int lane = tid & 63;
    const int wid  = tid >> 6;
    const int lr   = lane & 15;
    const int g    = lane >> 4;
    const int wm   = (wid >> 1) * 64;
    const int wn   = (wid & 1) * 64;
    const int m0   = blockIdx.x * 128;
    const int n0   = blockIdx.y * 128;

    f32x4 acc[4][4];
    #pragma unroll
    for (int i = 0; i < 4; ++i)
        #pragma unroll
        for (int j = 0; j < 4; ++j) acc[i][j] = (f32x4){0.f, 0.f, 0.f, 0.f};

    for (int k0 = 0; k0 < DIM; k0 += 64) {
        #pragma unroll
        for (int it = 0; it < 4; ++it) {
            int p   = tid + it * 256;
            int row = p >> 3;
            int c   = (p & 7) ^ (row & 7);
            gload16(a  + (size_t)(m0 + row) * DIM + k0 + c*8, As + p*8);
            gload16(wb + (size_t)(n0 + row) * DIM + k0 + c*8, Bs + p*8);
        }
        __syncthreads();
        #pragma unroll
        for (int kk = 0; kk < 2; ++kk) {
            bf16x8 af[4], bfr[4];
            #pragma unroll
            for (int i = 0; i < 4; ++i) {
                int row = wm + i*16 + lr;
                af[i] = *(const bf16x8*)(As + row*64 + (((kk*4 + g) ^ (row & 7)) << 3));
            }
            #pragma unroll
            for (int j = 0; j < 4; ++j) {
                int row = wn + j*16 + lr;
                bfr[j] = *(const bf16x8*)(Bs + row*64 + (((kk*4 + g) ^ (row & 7)) << 3));
            }
            #pragma unroll
            for (int i = 0; i < 4; ++i)
                #pragma unroll
                for (int j = 0; j < 4; ++j)
                    acc[i][j] = __builtin_amdgcn_mfma_f32_16x16x32_bf16(af[i], bfr[j], acc[i][j], 0, 0, 0);
        }
        __syncthreads();
    }

    #pragma unroll
    for (int i = 0; i < 4; ++i)
        #pragma unroll
        for (int j = 0; j < 4; ++j)
            #pragma unroll
            for (int v = 0; v < 4; ++v) {
                int row = m0 + wm + i*16 + g*4 + v;
                int col = n0 + wn + j*16 + lr;
                out[(size_t)row * DIM + col] = acc[i][j][v] + bias[col];
            }
}

extern "C" void kernel_launch(void* const* d_in, const int* in_sizes, int n_in,
                              void* d_out, int out_size, void* d_ws, size_t ws_size,
                              hipStream_t stream)
{
    const float* x      = (const float*)d_in[0];
    const float* rcos   = (const float*)d_in[1];
    const float* rsin   = (const float*)d_in[2];
    const float* qkv_w  = (const float*)d_in[3];
    const float* qkv_b  = (const float*)d_in[4];
    const float* proj_w = (const float*)d_in[5];
    const float* proj_b = (const float*)d_in[6];
    float* out = (float*)d_out;

    const size_t BUF = (size_t)2 * NUM_HEADS * NTOK * HEAD_DIM;
    unsigned short* qb    = (unsigned short*)d_ws;
    unsigned short* kb    = qb + BUF;
    unsigned short* vtb   = kb + BUF;
    unsigned short* attnb = vtb + BUF;
    unsigned short* xbf   = attnb + BUF;
    unsigned short* wqkvb = xbf + (size_t)MTOT * DIM;
    unsigned short* wprjb = wqkvb + (size_t)3 * DIM * DIM;

    k_conv<<<dim3((MTOT*DIM)/2048), 256, 0, stream>>>(x, xbf, MTOT*DIM);
    k_conv<<<dim3((3*DIM*DIM)/2048), 256, 0, stream>>>(qkv_w, wqkvb, 3*DIM*DIM);
    k_conv<<<dim3((DIM*DIM)/2048), 256, 0, stream>>>(proj_w, wprjb, DIM*DIM);

    k_gemm_qkv<<<dim3(32, 24), 256, 0, stream>>>(xbf, wqkvb, qkv_b, rcos, rsin, qb, kb, vtb);
    k_attn<<<dim3(NTOK/128, 32), 256, 0, stream>>>(qb, kb, vtb, attnb);
    k_proj<<<dim3(32, 8), 256, 0, stream>>>(attnb, wprjb, proj_b, out);
}

// Round 4
// 142.546 us; speedup vs baseline: 2.4244x; 1.1926x over previous
//
#include <hip/hip_runtime.h>
#include <hip/hip_bf16.h>

#define NUM_HEADS 16
#define HEAD_DIM 64
#define DIM 1024
#define NTOK 2048
#define MTOT 4096

typedef __attribute__((ext_vector_type(8))) short bf16x8;
typedef __attribute__((ext_vector_type(4))) float f32x4;

// RNE float->bf16 via HIP intrinsic (compiler can fuse pairs into v_cvt_pk_bf16_f32)
__device__ __forceinline__ unsigned short f2bf(float f) {
    union { __hip_bfloat16 h; unsigned short u; } c;
    c.h = __float2bfloat16(f);
    return c.u;
}

__device__ __forceinline__ void gload16(const unsigned short* g, unsigned short* l) {
    __builtin_amdgcn_global_load_lds(
        (const __attribute__((address_space(1))) void*)g,
        (__attribute__((address_space(3))) void*)l, 16, 0, 0);
}

// ---------------- Kernel 0: fp32 -> bf16 convert ----------------
__global__ __launch_bounds__(256) void k_conv(const float* __restrict__ src,
                                              unsigned short* __restrict__ dst, int n)
{
    int i = (blockIdx.x * 256 + threadIdx.x) * 8;
    if (i >= n) return;
    float4 a = *(const float4*)(src + i);
    float4 b = *(const float4*)(src + i + 4);
    union { unsigned short us[8]; uint4 u4; } p;
    p.us[0] = f2bf(a.x); p.us[1] = f2bf(a.y); p.us[2] = f2bf(a.z); p.us[3] = f2bf(a.w);
    p.us[4] = f2bf(b.x); p.us[5] = f2bf(b.y); p.us[6] = f2bf(b.z); p.us[7] = f2bf(b.w);
    *(uint4*)(dst + i) = p.u4;
}

// ---------------- Kernel 1: QKV GEMM + bias + RoPE + layout ----------------
// 128x128 tile, BK=64, swizzled LDS (chunk c -> c^(row&7) per 128B row).
// q scaled by 0.125*log2(e) so attention can use exp2 directly.
__global__ __launch_bounds__(256) void k_gemm_qkv(
    const unsigned short* __restrict__ xb, const unsigned short* __restrict__ wb,
    const float* __restrict__ bias, const float* __restrict__ rcos,
    const float* __restrict__ rsin,
    unsigned short* __restrict__ qb, unsigned short* __restrict__ kb,
    unsigned short* __restrict__ vtb)
{
    __shared__ __align__(16) unsigned char smem[34816];
    unsigned short* As = (unsigned short*)smem;            // [128][64] swizzled
    unsigned short* Bs = (unsigned short*)(smem + 16384);

    const int tid  = threadIdx.x;
    const int lane = tid & 63;
    const int wid  = tid >> 6;
    const int lr   = lane & 15;
    const int g    = lane >> 4;
    const int wm   = (wid >> 1) * 64;
    const int wn   = (wid & 1) * 64;
    const int m0   = blockIdx.x * 128;
    const int n0   = blockIdx.y * 128;

    f32x4 acc[4][4];
    #pragma unroll
    for (int i = 0; i < 4; ++i)
        #pragma unroll
        for (int j = 0; j < 4; ++j) acc[i][j] = (f32x4){0.f, 0.f, 0.f, 0.f};

    for (int k0 = 0; k0 < DIM; k0 += 64) {
        #pragma unroll
        for (int it = 0; it < 4; ++it) {
            int p   = tid + it * 256;
            int row = p >> 3;
            int c   = (p & 7) ^ (row & 7);
            gload16(xb + (size_t)(m0 + row) * DIM + k0 + c*8, As + p*8);
            gload16(wb + (size_t)(n0 + row) * DIM + k0 + c*8, Bs + p*8);
        }
        __syncthreads();
        #pragma unroll
        for (int kk = 0; kk < 2; ++kk) {
            bf16x8 af[4], bfr[4];
            #pragma unroll
            for (int i = 0; i < 4; ++i) {
                int row = wm + i*16 + lr;
                af[i] = *(const bf16x8*)(As + row*64 + (((kk*4 + g) ^ (row & 7)) << 3));
            }
            #pragma unroll
            for (int j = 0; j < 4; ++j) {
                int row = wn + j*16 + lr;
                bfr[j] = *(const bf16x8*)(Bs + row*64 + (((kk*4 + g) ^ (row & 7)) << 3));
            }
            #pragma unroll
            for (int i = 0; i < 4; ++i)
                #pragma unroll
                for (int j = 0; j < 4; ++j)
                    acc[i][j] = __builtin_amdgcn_mfma_f32_16x16x32_bf16(af[i], bfr[j], acc[i][j], 0, 0, 0);
        }
        __syncthreads();
    }

    const int sect = n0 >> 10;                 // 0=q, 1=k, 2=v
    float bq[4];
    #pragma unroll
    for (int j = 0; j < 4; ++j) bq[j] = bias[n0 + wn + j*16 + lr];

    if (sect < 2) {
        unsigned short* dst = sect ? kb : qb;
        // q: fold softmax scale AND log2(e) so attn uses exp2
        const float sc = sect ? 1.0f : 0.125f * 1.44269504088896f;
        const int h = ((n0 & 1023) + wn) >> 6;
        #pragma unroll
        for (int i = 0; i < 4; ++i) {
            #pragma unroll
            for (int v = 0; v < 4; ++v) {
                int gm = m0 + wm + i*16 + g*4 + v;
                int b  = gm >> 11, n = gm & 2047;
                size_t base = ((size_t)(b*NUM_HEADS + h) * NTOK + n) << 6;
                #pragma unroll
                for (int j = 0; j < 4; ++j) {
                    int d = j*16 + lr;
                    float val = acc[i][j][v] + bq[j];
                    float vp  = acc[i][j^2][v] + bq[j^2];
                    float rot = (j < 2) ? -vp : vp;
                    float c = rcos[n*64 + d], s = rsin[n*64 + d];
                    dst[base + d] = f2bf((val * c + rot * s) * sc);
                }
            }
        }
    } else {
        unsigned short (*vt)[136] = (unsigned short (*)[136])smem;
        __syncthreads();
        #pragma unroll
        for (int i = 0; i < 4; ++i)
            #pragma unroll
            for (int j = 0; j < 4; ++j)
                #pragma unroll
                for (int v = 0; v < 4; ++v) {
                    int row = wm + i*16 + g*4 + v;
                    int c   = wn + j*16 + lr;
                    vt[c][row] = f2bf(acc[i][j][v] + bq[j]);
                }
        __syncthreads();
        const int b = m0 >> 11;
        const int nbase = m0 & 2047;
        #pragma unroll
        for (int it = 0; it < 8; ++it) {
            int c   = (tid >> 4) + it * 16;
            int sc2 = (n0 & 1023) + c;
            int hh  = sc2 >> 6, d = sc2 & 63;
            int nloc = (tid & 15) * 8;
            uint4 val = *(uint4*)&vt[c][nloc];
            *(uint4*)(vtb + ((size_t)(b*NUM_HEADS + hh) * HEAD_DIM + d) * NTOK + nbase + nloc) = val;
        }
    }
}

// ---------------- Kernel 2: flash attention ----------------
// 64 q-rows/block, 4 waves x 16 rows, grid 1024 blocks (4/CU, 16 waves/CU).
// KV tiles of 64, double-buffered swizzled LDS, exp2 domain, lazy row-max.
__global__ __launch_bounds__(256, 4) void k_attn(
    const unsigned short* __restrict__ qb, const unsigned short* __restrict__ kb,
    const unsigned short* __restrict__ vtb, unsigned short* __restrict__ attnb)
{
    __shared__ __align__(16) unsigned short kbuf[2][4096];
    __shared__ __align__(16) unsigned short vbuf[2][4096];
    __shared__ __align__(16) unsigned short pbuf[4][1024];   // per-wave [16][64] swizzled

    const int tid  = threadIdx.x;
    const int lane = tid & 63;
    const int w    = tid >> 6;
    const int g    = lane >> 4;
    const int lr   = lane & 15;
    const int q0   = blockIdx.x * 64;
    const int bh   = blockIdx.y;
    const int b    = bh >> 4, h = bh & 15;

    const unsigned short* kbase = kb  + (size_t)bh * NTOK * 64;
    const unsigned short* vbase = vtb + (size_t)bh * HEAD_DIM * NTOK;

    bf16x8 qa[2];
    {
        size_t qrow = ((size_t)bh * NTOK + q0 + w*16 + lr) * 64;
        #pragma unroll
        for (int kk = 0; kk < 2; ++kk)
            qa[kk] = *(const bf16x8*)(qb + qrow + kk*32 + g*8);
    }

    f32x4 o[4];
    float m_[4], lsum[4];
    #pragma unroll
    for (int fd = 0; fd < 4; ++fd) o[fd] = (f32x4){0.f, 0.f, 0.f, 0.f};
    #pragma unroll
    for (int v = 0; v < 4; ++v) { m_[v] = -1e30f; lsum[v] = 0.f; }

    // stage tile 0
    #pragma unroll
    for (int hp = 0; hp < 2; ++hp) {
        int p   = tid + hp * 256;
        int row = p >> 3;
        int c   = (p & 7) ^ (row & 7);
        gload16(kbase + (size_t)row*64 + c*8, &kbuf[0][p*8]);
        gload16(vbase + (size_t)row*NTOK + c*8, &vbuf[0][p*8]);
    }
    __syncthreads();

    int cur = 0;
    for (int t = 0; t < NTOK/64; ++t) {
        if (t < NTOK/64 - 1) {
            int kvn = (t + 1) * 64;
            #pragma unroll
            for (int hp = 0; hp < 2; ++hp) {
                int p   = tid + hp * 256;
                int row = p >> 3;
                int c   = (p & 7) ^ (row & 7);
                gload16(kbase + (size_t)(kvn + row)*64 + c*8, &kbuf[cur^1][p*8]);
                gload16(vbase + (size_t)row*NTOK + kvn + c*8, &vbuf[cur^1][p*8]);
            }
        }

        // ---- QK^T (scores already in log2 domain) ----
        f32x4 s[4];
        #pragma unroll
        for (int fn = 0; fn < 4; ++fn) s[fn] = (f32x4){0.f, 0.f, 0.f, 0.f};
        #pragma unroll
        for (int kk = 0; kk < 2; ++kk) {
            bf16x8 kf[4];
            #pragma unroll
            for (int fn = 0; fn < 4; ++fn) {
                int row = fn*16 + lr;
                kf[fn] = *(const bf16x8*)&kbuf[cur][row*64 + (((kk*4 + g) ^ (row & 7)) << 3)];
            }
            #pragma unroll
            for (int fn = 0; fn < 4; ++fn)
                s[fn] = __builtin_amdgcn_mfma_f32_16x16x32_bf16(qa[kk], kf[fn], s[fn], 0, 0, 0);
        }

        // ---- lazy row-max: per-lane max + threshold; full reduce only if needed ----
        float lmax[4];
        int need = 0;
        #pragma unroll
        for (int v = 0; v < 4; ++v) {
            lmax[v] = fmaxf(fmaxf(s[0][v], s[1][v]), fmaxf(s[2][v], s[3][v]));
            need |= (lmax[v] > m_[v] + 8.f);
        }
        if (__any(need)) {
            #pragma unroll
            for (int v = 0; v < 4; ++v) {
                float mx = lmax[v];
                mx = fmaxf(mx, __shfl_xor(mx, 1));
                mx = fmaxf(mx, __shfl_xor(mx, 2));
                mx = fmaxf(mx, __shfl_xor(mx, 4));
                mx = fmaxf(mx, __shfl_xor(mx, 8));
                float mn  = fmaxf(m_[v], mx);
                float scl = __builtin_amdgcn_exp2f(m_[v] - mn);
                m_[v] = mn;
                lsum[v] *= scl;
                #pragma unroll
                for (int fd = 0; fd < 4; ++fd) o[fd][v] *= scl;
            }
        }

        // ---- P = exp2(s - m) -> wave-private swizzled pbuf ----
        unsigned short* pw = pbuf[w];
        #pragma unroll
        for (int fn = 0; fn < 4; ++fn)
            #pragma unroll
            for (int v = 0; v < 4; ++v) {
                float p = __builtin_amdgcn_exp2f(s[fn][v] - m_[v]);
                lsum[v] += p;
                int row = g*4 + v;
                int col = fn*16 + lr;
                pw[row*64 + (((col >> 3) ^ (row & 7)) << 3) + (col & 7)] = f2bf(p);
            }

        // ---- PV ----
        #pragma unroll
        for (int kk = 0; kk < 2; ++kk) {
            bf16x8 pa, vf[4];
            pa = *(const bf16x8*)&pw[lr*64 + (((kk*4 + g) ^ (lr & 7)) << 3)];
            #pragma unroll
            for (int fd = 0; fd < 4; ++fd) {
                int row = fd*16 + lr;
                vf[fd] = *(const bf16x8*)&vbuf[cur][row*64 + (((kk*4 + g) ^ (row & 7)) << 3)];
            }
            #pragma unroll
            for (int fd = 0; fd < 4; ++fd)
                o[fd] = __builtin_amdgcn_mfma_f32_16x16x32_bf16(pa, vf[fd], o[fd], 0, 0, 0);
        }
        __syncthreads();
        cur ^= 1;
    }

    // final: reduce lsum across 16-lane group, normalize, write
    #pragma unroll
    for (int v = 0; v < 4; ++v) {
        float l = lsum[v];
        l += __shfl_xor(l, 1);
        l += __shfl_xor(l, 2);
        l += __shfl_xor(l, 4);
        l += __shfl_xor(l, 8);
        lsum[v] = 1.0f / l;
    }
    #pragma unroll
    for (int fd = 0; fd < 4; ++fd)
        #pragma unroll
        for (int v = 0; v < 4; ++v) {
            int n = q0 + w*16 + g*4 + v;
            attnb[((size_t)(b*NTOK + n)) * DIM + h*HEAD_DIM + fd*16 + lr] =
                f2bf(o[fd][v] * lsum[v]);
        }
}

// ---------------- Kernel 3: output projection ----------------
__global__ __launch_bounds__(256) void k_proj(
    const unsigned short* __restrict__ a, const unsigned short* __restrict__ wb,
    const float* __restrict__ bias, float* __restrict__ out)
{
    __shared__ __align__(16) unsigned short As[8192];
    __shared__ __align__(16) unsigned short Bs[8192];

    const int tid  = threadIdx.x;
    const int lane = tid & 63;
    const int wid  = tid >> 6;
    const int lr   = lane & 15;
    const int g    = lane >> 4;
    const int wm   = (wid >> 1) * 64;
    const int wn   = (wid & 1) * 64;
    const int m0   = blockIdx.x * 128;
    const int n0   = blockIdx.y * 128;

    f32x4 acc[4][4];
    #pragma unroll
    for (int i = 0; i < 4; ++i)
        #pragma unroll
        for (int j = 0; j < 4; ++j) acc[i][j] = (f32x4){0.f, 0.f, 0.f, 0.f};

    for (int k0 = 0; k0 < DIM; k0 += 64) {
        #pragma unroll
        for (int it = 0; it < 4; ++it) {
            int p   = tid + it * 256;
            int row = p >> 3;
            int c   = (p & 7) ^ (row & 7);
            gload16(a  + (size_t)(m0 + row) * DIM + k0 + c*8, As + p*8);
            gload16(wb + (size_t)(n0 + row) * DIM + k0 + c*8, Bs + p*8);
        }
        __syncthreads();
        #pragma unroll
        for (int kk = 0; kk < 2; ++kk) {
            bf16x8 af[4], bfr[4];
            #pragma unroll
            for (int i = 0; i < 4; ++i) {
                int row = wm + i*16 + lr;
                af[i] = *(const bf16x8*)(As + row*64 + (((kk*4 + g) ^ (row & 7)) << 3));
            }
            #pragma unroll
            for (int j = 0; j < 4; ++j) {
                int row = wn + j*16 + lr;
                bfr[j] = *(const bf16x8*)(Bs + row*64 + (((kk*4 + g) ^ (row & 7)) << 3));
            }
            #pragma unroll
            for (int i = 0; i < 4; ++i)
                #pragma unroll
                for (int j = 0; j < 4; ++j)
                    acc[i][j] = __builtin_amdgcn_mfma_f32_16x16x32_bf16(af[i], bfr[j], acc[i][j], 0, 0, 0);
        }
        __syncthreads();
    }

    #pragma unroll
    for (int i = 0; i < 4; ++i)
        #pragma unroll
        for (int j = 0; j < 4; ++j)
            #pragma unroll
            for (int v = 0; v < 4; ++v) {
                int row = m0 + wm + i*16 + g*4 + v;
                int col = n0 + wn + j*16 + lr;
                out[(size_t)row * DIM + col] = acc[i][j][v] + bias[col];
            }
}

extern "C" void kernel_launch(void* const* d_in, const int* in_sizes, int n_in,
                              void* d_out, int out_size, void* d_ws, size_t ws_size,
                              hipStream_t stream)
{
    const float* x      = (const float*)d_in[0];
    const float* rcos   = (const float*)d_in[1];
    const float* rsin   = (const float*)d_in[2];
    const float* qkv_w  = (const float*)d_in[3];
    const float* qkv_b  = (const float*)d_in[4];
    const float* proj_w = (const float*)d_in[5];
    const float* proj_b = (const float*)d_in[6];
    float* out = (float*)d_out;

    const size_t BUF = (size_t)2 * NUM_HEADS * NTOK * HEAD_DIM;
    unsigned short* qb    = (unsigned short*)d_ws;
    unsigned short* kb    = qb + BUF;
    unsigned short* vtb   = kb + BUF;
    unsigned short* attnb = vtb + BUF;
    unsigned short* xbf   = attnb + BUF;
    unsigned short* wqkvb = xbf + (size_t)MTOT * DIM;
    unsigned short* wprjb = wqkvb + (size_t)3 * DIM * DIM;

    k_conv<<<dim3((MTOT*DIM)/2048), 256, 0, stream>>>(x, xbf, MTOT*DIM);
    k_conv<<<dim3((3*DIM*DIM)/2048), 256, 0, stream>>>(qkv_w, wqkvb, 3*DIM*DIM);
    k_conv<<<dim3((DIM*DIM)/2048), 256, 0, stream>>>(proj_w, wprjb, DIM*DIM);

    k_gemm_qkv<<<dim3(32, 24), 256, 0, stream>>>(xbf, wqkvb, qkv_b, rcos, rsin, qb, kb, vtb);
    k_attn<<<dim3(NTOK/64, 32), 256, 0, stream>>>(qb, kb, vtb, attnb);
    k_proj<<<dim3(32, 8), 256, 0, stream>>>(attnb, wprjb, proj_b, out);
}

// Round 5
// 135.707 us; speedup vs baseline: 2.5466x; 1.0504x over previous
//
#include <hip/hip_runtime.h>
#include <hip/hip_bf16.h>

#define NUM_HEADS 16
#define HEAD_DIM 64
#define DIM 1024
#define NTOK 2048
#define MTOT 4096

typedef __attribute__((ext_vector_type(8))) short bf16x8;
typedef __attribute__((ext_vector_type(4))) float f32x4;

__device__ __forceinline__ unsigned short f2bf(float f) {
    union { __hip_bfloat16 h; unsigned short u; } c;
    c.h = __float2bfloat16(f);
    return c.u;
}

__device__ __forceinline__ void gload16(const unsigned short* g, unsigned short* l) {
    __builtin_amdgcn_global_load_lds(
        (const __attribute__((address_space(1))) void*)g,
        (__attribute__((address_space(3))) void*)l, 16, 0, 0);
}

// ---------------- Kernel 0: fused fp32 -> bf16 convert (3 buffers, 1 launch) ----------------
__global__ __launch_bounds__(256) void k_conv3(
    const float* __restrict__ s0, unsigned short* __restrict__ d0, int n0,
    const float* __restrict__ s1, unsigned short* __restrict__ d1, int n1,
    const float* __restrict__ s2, unsigned short* __restrict__ d2, int n2)
{
    int blk = blockIdx.x;
    int b0 = n0 >> 11, b1 = n1 >> 11;
    const float* s; unsigned short* d; int i;
    if (blk < b0)            { s = s0; d = d0; i = blk; }
    else if (blk < b0 + b1)  { s = s1; d = d1; i = blk - b0; }
    else                     { s = s2; d = d2; i = blk - b0 - b1; }
    int idx = (i * 256 + threadIdx.x) * 8;
    float4 a = *(const float4*)(s + idx);
    float4 b = *(const float4*)(s + idx + 4);
    union { unsigned short us[8]; uint4 u4; } p;
    p.us[0] = f2bf(a.x); p.us[1] = f2bf(a.y); p.us[2] = f2bf(a.z); p.us[3] = f2bf(a.w);
    p.us[4] = f2bf(b.x); p.us[5] = f2bf(b.y); p.us[6] = f2bf(b.z); p.us[7] = f2bf(b.w);
    *(uint4*)(d + idx) = p.u4;
}

// ---------------- Kernel 1: QKV GEMM + bias + RoPE + layout ----------------
__global__ __launch_bounds__(256) void k_gemm_qkv(
    const unsigned short* __restrict__ xb, const unsigned short* __restrict__ wb,
    const float* __restrict__ bias, const float* __restrict__ rcos,
    const float* __restrict__ rsin,
    unsigned short* __restrict__ qb, unsigned short* __restrict__ kb,
    unsigned short* __restrict__ vtb)
{
    __shared__ __align__(16) unsigned char smem[34816];
    unsigned short* As = (unsigned short*)smem;            // [128][64] swizzled
    unsigned short* Bs = (unsigned short*)(smem + 16384);

    const int tid  = threadIdx.x;
    const int lane = tid & 63;
    const int wid  = tid >> 6;
    const int lr   = lane & 15;
    const int g    = lane >> 4;
    const int wm   = (wid >> 1) * 64;
    const int wn   = (wid & 1) * 64;
    const int m0   = blockIdx.x * 128;
    const int n0   = blockIdx.y * 128;

    f32x4 acc[4][4];
    #pragma unroll
    for (int i = 0; i < 4; ++i)
        #pragma unroll
        for (int j = 0; j < 4; ++j) acc[i][j] = (f32x4){0.f, 0.f, 0.f, 0.f};

    for (int k0 = 0; k0 < DIM; k0 += 64) {
        #pragma unroll
        for (int it = 0; it < 4; ++it) {
            int p   = tid + it * 256;
            int row = p >> 3;
            int c   = (p & 7) ^ (row & 7);
            gload16(xb + (size_t)(m0 + row) * DIM + k0 + c*8, As + p*8);
            gload16(wb + (size_t)(n0 + row) * DIM + k0 + c*8, Bs + p*8);
        }
        __syncthreads();
        #pragma unroll
        for (int kk = 0; kk < 2; ++kk) {
            bf16x8 af[4], bfr[4];
            #pragma unroll
            for (int i = 0; i < 4; ++i) {
                int row = wm + i*16 + lr;
                af[i] = *(const bf16x8*)(As + row*64 + (((kk*4 + g) ^ (row & 7)) << 3));
            }
            #pragma unroll
            for (int j = 0; j < 4; ++j) {
                int row = wn + j*16 + lr;
                bfr[j] = *(const bf16x8*)(Bs + row*64 + (((kk*4 + g) ^ (row & 7)) << 3));
            }
            #pragma unroll
            for (int i = 0; i < 4; ++i)
                #pragma unroll
                for (int j = 0; j < 4; ++j)
                    acc[i][j] = __builtin_amdgcn_mfma_f32_16x16x32_bf16(af[i], bfr[j], acc[i][j], 0, 0, 0);
        }
        __syncthreads();
    }

    const int sect = n0 >> 10;                 // 0=q, 1=k, 2=v
    float bq[4];
    #pragma unroll
    for (int j = 0; j < 4; ++j) bq[j] = bias[n0 + wn + j*16 + lr];

    if (sect < 2) {
        unsigned short* dst = sect ? kb : qb;
        const float sc = sect ? 1.0f : 0.125f * 1.44269504088896f;  // fold scale+log2e into q
        const int h = ((n0 & 1023) + wn) >> 6;
        #pragma unroll
        for (int i = 0; i < 4; ++i) {
            #pragma unroll
            for (int v = 0; v < 4; ++v) {
                int gm = m0 + wm + i*16 + g*4 + v;
                int b  = gm >> 11, n = gm & 2047;
                size_t base = ((size_t)(b*NUM_HEADS + h) * NTOK + n) << 6;
                #pragma unroll
                for (int j = 0; j < 4; ++j) {
                    int d = j*16 + lr;
                    float val = acc[i][j][v] + bq[j];
                    float vp  = acc[i][j^2][v] + bq[j^2];
                    float rot = (j < 2) ? -vp : vp;
                    float c = rcos[n*64 + d], s = rsin[n*64 + d];
                    dst[base + d] = f2bf((val * c + rot * s) * sc);
                }
            }
        }
    } else {
        unsigned short (*vt)[136] = (unsigned short (*)[136])smem;
        __syncthreads();
        #pragma unroll
        for (int i = 0; i < 4; ++i)
            #pragma unroll
            for (int j = 0; j < 4; ++j)
                #pragma unroll
                for (int v = 0; v < 4; ++v) {
                    int row = wm + i*16 + g*4 + v;
                    int c   = wn + j*16 + lr;
                    vt[c][row] = f2bf(acc[i][j][v] + bq[j]);
                }
        __syncthreads();
        const int b = m0 >> 11;
        const int nbase = m0 & 2047;
        #pragma unroll
        for (int it = 0; it < 8; ++it) {
            int c   = (tid >> 4) + it * 16;
            int sc2 = (n0 & 1023) + c;
            int hh  = sc2 >> 6, d = sc2 & 63;
            int nloc = (tid & 15) * 8;
            uint4 val = *(uint4*)&vt[c][nloc];
            *(uint4*)(vtb + ((size_t)(b*NUM_HEADS + hh) * HEAD_DIM + d) * NTOK + nbase + nloc) = val;
        }
    }
}

// ---------------- Kernel 2: flash attention ----------------
// 64 q-rows/block, 4 waves x 16 rows, 1024 blocks. All LDS offsets hoisted;
// KV loop unrolled x2 so buffer toggle is a compile-time +8192 (ds imm offset).
// LDS byte layout: K dbuf [0,16384), V dbuf [16384,32768), P per-wave [32768,40960)
__global__ __launch_bounds__(256, 4) void k_attn(
    const unsigned short* __restrict__ qb, const unsigned short* __restrict__ kb,
    const unsigned short* __restrict__ vtb, unsigned short* __restrict__ attnb)
{
    __shared__ __align__(16) char sb[40960];

    const int tid  = threadIdx.x;
    const int lane = tid & 63;
    const int w    = tid >> 6;
    const int g    = lane >> 4;
    const int lr   = lane & 15;
    const int q0   = blockIdx.x * 64;
    const int bh   = blockIdx.y;
    const int b    = bh >> 4, h = bh & 15;

    // ---- hoisted LDS byte offsets (loop-invariant) ----
    int kfoff[2][4], vfoff[2][4], paoff[2], pwoff[4][4];
    #pragma unroll
    for (int kk = 0; kk < 2; ++kk) {
        #pragma unroll
        for (int fn = 0; fn < 4; ++fn) {
            int row = fn*16 + lr;
            int sw  = ((kk*4 + g) ^ (row & 7)) << 4;
            kfoff[kk][fn] = row*128 + sw;
            vfoff[kk][fn] = 16384 + row*128 + sw;
        }
        paoff[kk] = 32768 + w*2048 + lr*128 + (((kk*4 + g) ^ (lr & 7)) << 4);
    }
    #pragma unroll
    for (int fn = 0; fn < 4; ++fn)
        #pragma unroll
        for (int v = 0; v < 4; ++v) {
            int row = g*4 + v, col = fn*16 + lr;
            pwoff[fn][v] = 32768 + w*2048 + row*128 + (((col >> 3) ^ (row & 7)) << 4) + (col & 7)*2;
        }

    // ---- staging pointers (advance by stride each tile) ----
    const unsigned short* gk[2];
    const unsigned short* gv[2];
    char* dk[2]; char* dv[2];
    {
        const unsigned short* kbase = kb  + (size_t)bh * NTOK * 64;
        const unsigned short* vbase = vtb + (size_t)bh * HEAD_DIM * NTOK;
        #pragma unroll
        for (int hp = 0; hp < 2; ++hp) {
            int p   = tid + hp * 256;
            int row = p >> 3;
            int c   = (p & 7) ^ (row & 7);
            gk[hp] = kbase + row*64 + c*8;
            gv[hp] = vbase + (size_t)row*NTOK + c*8;
            dk[hp] = sb + p*16;
            dv[hp] = sb + 16384 + p*16;
        }
    }

    bf16x8 qa[2];
    {
        size_t qrow = ((size_t)bh * NTOK + q0 + w*16 + lr) * 64;
        #pragma unroll
        for (int kk = 0; kk < 2; ++kk)
            qa[kk] = *(const bf16x8*)(qb + qrow + kk*32 + g*8);
    }

    f32x4 o[4];
    float m_[4], lsum[4];
    #pragma unroll
    for (int fd = 0; fd < 4; ++fd) o[fd] = (f32x4){0.f, 0.f, 0.f, 0.f};
    #pragma unroll
    for (int v = 0; v < 4; ++v) { m_[v] = -1e30f; lsum[v] = 0.f; }

    // stage tile 0 into buffer 0
    #pragma unroll
    for (int hp = 0; hp < 2; ++hp) {
        gload16(gk[hp], (unsigned short*)dk[hp]);
        gload16(gv[hp], (unsigned short*)dv[hp]);
        gk[hp] += 4096; gv[hp] += 64;
    }
    __syncthreads();

#define ATTN_ITER(X, DO_STAGE)                                                   \
    {                                                                            \
        if (DO_STAGE) {                                                          \
            _Pragma("unroll")                                                    \
            for (int hp = 0; hp < 2; ++hp) {                                     \
                gload16(gk[hp], (unsigned short*)(dk[hp] + ((X) ^ 8192)));       \
                gload16(gv[hp], (unsigned short*)(dv[hp] + ((X) ^ 8192)));       \
                gk[hp] += 4096; gv[hp] += 64;                                    \
            }                                                                    \
        }                                                                        \
        f32x4 s_[4];                                                             \
        _Pragma("unroll")                                                        \
        for (int fn = 0; fn < 4; ++fn) s_[fn] = (f32x4){0.f, 0.f, 0.f, 0.f};     \
        _Pragma("unroll")                                                        \
        for (int kk = 0; kk < 2; ++kk) {                                         \
            bf16x8 kf[4];                                                        \
            _Pragma("unroll")                                                    \
            for (int fn = 0; fn < 4; ++fn)                                       \
                kf[fn] = *(const bf16x8*)(sb + kfoff[kk][fn] + (X));             \
            __builtin_amdgcn_s_setprio(1);                                       \
            _Pragma("unroll")                                                    \
            for (int fn = 0; fn < 4; ++fn)                                       \
                s_[fn] = __builtin_amdgcn_mfma_f32_16x16x32_bf16(qa[kk], kf[fn], s_[fn], 0, 0, 0); \
            __builtin_amdgcn_s_setprio(0);                                       \
        }                                                                        \
        float lmax[4]; int need = 0;                                             \
        _Pragma("unroll")                                                        \
        for (int v = 0; v < 4; ++v) {                                            \
            lmax[v] = fmaxf(fmaxf(fmaxf(s_[0][v], s_[1][v]), s_[2][v]), s_[3][v]); \
            need |= (lmax[v] > m_[v] + 8.f);                                     \
        }                                                                        \
        if (__any(need)) {                                                       \
            _Pragma("unroll")                                                    \
            for (int v = 0; v < 4; ++v) {                                        \
                float mx = lmax[v];                                              \
                mx = fmaxf(mx, __shfl_xor(mx, 1));                               \
                mx = fmaxf(mx, __shfl_xor(mx, 2));                               \
                mx = fmaxf(mx, __shfl_xor(mx, 4));                               \
                mx = fmaxf(mx, __shfl_xor(mx, 8));                               \
                float mn  = fmaxf(m_[v], mx);                                    \
                float scl = __builtin_amdgcn_exp2f(m_[v] - mn);                  \
                m_[v] = mn;                                                      \
                lsum[v] *= scl;                                                  \
                _Pragma("unroll")                                                \
                for (int fd = 0; fd < 4; ++fd) o[fd][v] *= scl;                  \
            }                                                                    \
        }                                                                        \
        _Pragma("unroll")                                                        \
        for (int fn = 0; fn < 4; ++fn)                                           \
            _Pragma("unroll")                                                    \
            for (int v = 0; v < 4; ++v) {                                        \
                float p = __builtin_amdgcn_exp2f(s_[fn][v] - m_[v]);             \
                lsum[v] += p;                                                    \
                *(unsigned short*)(sb + pwoff[fn][v]) = f2bf(p);                 \
            }                                                                    \
        _Pragma("unroll")                                                        \
        for (int kk = 0; kk < 2; ++kk) {                                         \
            bf16x8 pa = *(const bf16x8*)(sb + paoff[kk]);                        \
            bf16x8 vf[4];                                                        \
            _Pragma("unroll")                                                    \
            for (int fd = 0; fd < 4; ++fd)                                       \
                vf[fd] = *(const bf16x8*)(sb + vfoff[kk][fd] + (X));             \
            __builtin_amdgcn_s_setprio(1);                                       \
            _Pragma("unroll")                                                    \
            for (int fd = 0; fd < 4; ++fd)                                       \
                o[fd] = __builtin_amdgcn_mfma_f32_16x16x32_bf16(pa, vf[fd], o[fd], 0, 0, 0); \
            __builtin_amdgcn_s_setprio(0);                                       \
        }                                                                        \
        __syncthreads();                                                         \
    }

    #pragma unroll 1
    for (int t = 0; t < NTOK/64; t += 2) {
        ATTN_ITER(0,    true);
        ATTN_ITER(8192, (t + 2 < NTOK/64));
    }
#undef ATTN_ITER

    // final: reduce lsum across 16-lane group, normalize, write
    #pragma unroll
    for (int v = 0; v < 4; ++v) {
        float l = lsum[v];
        l += __shfl_xor(l, 1);
        l += __shfl_xor(l, 2);
        l += __shfl_xor(l, 4);
        l += __shfl_xor(l, 8);
        lsum[v] = 1.0f / l;
    }
    #pragma unroll
    for (int fd = 0; fd < 4; ++fd)
        #pragma unroll
        for (int v = 0; v < 4; ++v) {
            int n = q0 + w*16 + g*4 + v;
            attnb[((size_t)(b*NTOK + n)) * DIM + h*HEAD_DIM + fd*16 + lr] =
                f2bf(o[fd][v] * lsum[v]);
        }
}

// ---------------- Kernel 3: output projection ----------------
__global__ __launch_bounds__(256) void k_proj(
    const unsigned short* __restrict__ a, const unsigned short* __restrict__ wb,
    const float* __restrict__ bias, float* __restrict__ out)
{
    __shared__ __align__(16) unsigned short As[8192];
    __shared__ __align__(16) unsigned short Bs[8192];

    const int tid  = threadIdx.x;
    const int lane = tid & 63;
    const int wid  = tid >> 6;
    const int lr   = lane & 15;
    const int g    = lane >> 4;
    const int wm   = (wid >> 1) * 64;
    const int wn   = (wid & 1) * 64;
    const int m0   = blockIdx.x * 128;
    const int n0   = blockIdx.y * 128;

    f32x4 acc[4][4];
    #pragma unroll
    for (int i = 0; i < 4; ++i)
        #pragma unroll
        for (int j = 0; j < 4; ++j) acc[i][j] = (f32x4){0.f, 0.f, 0.f, 0.f};

    for (int k0 = 0; k0 < DIM; k0 += 64) {
        #pragma unroll
        for (int it = 0; it < 4; ++it) {
            int p   = tid + it * 256;
            int row = p >> 3;
            int c   = (p & 7) ^ (row & 7);
            gload16(a  + (size_t)(m0 + row) * DIM + k0 + c*8, As + p*8);
            gload16(wb + (size_t)(n0 + row) * DIM + k0 + c*8, Bs + p*8);
        }
        __syncthreads();
        #pragma unroll
        for (int kk = 0; kk < 2; ++kk) {
            bf16x8 af[4], bfr[4];
            #pragma unroll
            for (int i = 0; i < 4; ++i) {
                int row = wm + i*16 + lr;
                af[i] = *(const bf16x8*)(As + row*64 + (((kk*4 + g) ^ (row & 7)) << 3));
            }
            #pragma unroll
            for (int j = 0; j < 4; ++j) {
                int row = wn + j*16 + lr;
                bfr[j] = *(const bf16x8*)(Bs + row*64 + (((kk*4 + g) ^ (row & 7)) << 3));
            }
            #pragma unroll
            for (int i = 0; i < 4; ++i)
                #pragma unroll
                for (int j = 0; j < 4; ++j)
                    acc[i][j] = __builtin_amdgcn_mfma_f32_16x16x32_bf16(af[i], bfr[j], acc[i][j], 0, 0, 0);
        }
        __syncthreads();
    }

    #pragma unroll
    for (int i = 0; i < 4; ++i)
        #pragma unroll
        for (int j = 0; j < 4; ++j)
            #pragma unroll
            for (int v = 0; v < 4; ++v) {
                int row = m0 + wm + i*16 + g*4 + v;
                int col = n0 + wn + j*16 + lr;
                out[(size_t)row * DIM + col] = acc[i][j][v] + bias[col];
            }
}

extern "C" void kernel_launch(void* const* d_in, const int* in_sizes, int n_in,
                              void* d_out, int out_size, void* d_ws, size_t ws_size,
                              hipStream_t stream)
{
    const float* x      = (const float*)d_in[0];
    const float* rcos   = (const float*)d_in[1];
    const float* rsin   = (const float*)d_in[2];
    const float* qkv_w  = (const float*)d_in[3];
    const float* qkv_b  = (const float*)d_in[4];
    const float* proj_w = (const float*)d_in[5];
    const float* proj_b = (const float*)d_in[6];
    float* out = (float*)d_out;

    const size_t BUF = (size_t)2 * NUM_HEADS * NTOK * HEAD_DIM;
    unsigned short* qb    = (unsigned short*)d_ws;
    unsigned short* kb    = qb + BUF;
    unsigned short* vtb   = kb + BUF;
    unsigned short* attnb = vtb + BUF;
    unsigned short* xbf   = attnb + BUF;
    unsigned short* wqkvb = xbf + (size_t)MTOT * DIM;
    unsigned short* wprjb = wqkvb + (size_t)3 * DIM * DIM;

    const int n0 = MTOT * DIM, n1 = 3 * DIM * DIM, n2 = DIM * DIM;
    k_conv3<<<dim3((n0 + n1 + n2) / 2048), 256, 0, stream>>>(
        x, xbf, n0, qkv_w, wqkvb, n1, proj_w, wprjb, n2);

    k_gemm_qkv<<<dim3(32, 24), 256, 0, stream>>>(xbf, wqkvb, qkv_b, rcos, rsin, qb, kb, vtb);
    k_attn<<<dim3(NTOK/64, 32), 256, 0, stream>>>(qb, kb, vtb, attnb);
    k_proj<<<dim3(32, 8), 256, 0, stream>>>(attnb, wprjb, proj_b, out);
}

// Round 6
// 127.904 us; speedup vs baseline: 2.7020x; 1.0610x over previous
//
#include <hip/hip_runtime.h>
#include <hip/hip_bf16.h>

#define NUM_HEADS 16
#define HEAD_DIM 64
#define DIM 1024
#define NTOK 2048
#define MTOT 4096

typedef __attribute__((ext_vector_type(8))) short bf16x8;
typedef __attribute__((ext_vector_type(4))) float f32x4;

__device__ __forceinline__ unsigned short f2bf(float f) {
    union { __hip_bfloat16 h; unsigned short u; } c;
    c.h = __float2bfloat16(f);
    return c.u;
}

__device__ __forceinline__ void gload16(const unsigned short* g, unsigned short* l) {
    __builtin_amdgcn_global_load_lds(
        (const __attribute__((address_space(1))) void*)g,
        (__attribute__((address_space(3))) void*)l, 16, 0, 0);
}

// ---------------- Kernel 0: fused fp32 -> bf16 convert (3 buffers, 1 launch) ----------------
__global__ __launch_bounds__(256) void k_conv3(
    const float* __restrict__ s0, unsigned short* __restrict__ d0, int n0,
    const float* __restrict__ s1, unsigned short* __restrict__ d1, int n1,
    const float* __restrict__ s2, unsigned short* __restrict__ d2, int n2)
{
    int blk = blockIdx.x;
    int b0 = n0 >> 11, b1 = n1 >> 11;
    const float* s; unsigned short* d; int i;
    if (blk < b0)            { s = s0; d = d0; i = blk; }
    else if (blk < b0 + b1)  { s = s1; d = d1; i = blk - b0; }
    else                     { s = s2; d = d2; i = blk - b0 - b1; }
    int idx = (i * 256 + threadIdx.x) * 8;
    float4 a = *(const float4*)(s + idx);
    float4 b = *(const float4*)(s + idx + 4);
    union { unsigned short us[8]; uint4 u4; } p;
    p.us[0] = f2bf(a.x); p.us[1] = f2bf(a.y); p.us[2] = f2bf(a.z); p.us[3] = f2bf(a.w);
    p.us[4] = f2bf(b.x); p.us[5] = f2bf(b.y); p.us[6] = f2bf(b.z); p.us[7] = f2bf(b.w);
    *(uint4*)(d + idx) = p.u4;
}

// ---------------- Kernel 1: QKV GEMM + bias + RoPE + layout ----------------
__global__ __launch_bounds__(256) void k_gemm_qkv(
    const unsigned short* __restrict__ xb, const unsigned short* __restrict__ wb,
    const float* __restrict__ bias, const float* __restrict__ rcos,
    const float* __restrict__ rsin,
    unsigned short* __restrict__ qb, unsigned short* __restrict__ kb,
    unsigned short* __restrict__ vtb)
{
    __shared__ __align__(16) unsigned char smem[34816];
    unsigned short* As = (unsigned short*)smem;            // [128][64] swizzled
    unsigned short* Bs = (unsigned short*)(smem + 16384);

    const int tid  = threadIdx.x;
    const int lane = tid & 63;
    const int wid  = tid >> 6;
    const int lr   = lane & 15;
    const int g    = lane >> 4;
    const int wm   = (wid >> 1) * 64;
    const int wn   = (wid & 1) * 64;
    const int m0   = blockIdx.x * 128;
    const int n0   = blockIdx.y * 128;

    f32x4 acc[4][4];
    #pragma unroll
    for (int i = 0; i < 4; ++i)
        #pragma unroll
        for (int j = 0; j < 4; ++j) acc[i][j] = (f32x4){0.f, 0.f, 0.f, 0.f};

    for (int k0 = 0; k0 < DIM; k0 += 64) {
        #pragma unroll
        for (int it = 0; it < 4; ++it) {
            int p   = tid + it * 256;
            int row = p >> 3;
            int c   = (p & 7) ^ (row & 7);
            gload16(xb + (size_t)(m0 + row) * DIM + k0 + c*8, As + p*8);
            gload16(wb + (size_t)(n0 + row) * DIM + k0 + c*8, Bs + p*8);
        }
        __syncthreads();
        #pragma unroll
        for (int kk = 0; kk < 2; ++kk) {
            bf16x8 af[4], bfr[4];
            #pragma unroll
            for (int i = 0; i < 4; ++i) {
                int row = wm + i*16 + lr;
                af[i] = *(const bf16x8*)(As + row*64 + (((kk*4 + g) ^ (row & 7)) << 3));
            }
            #pragma unroll
            for (int j = 0; j < 4; ++j) {
                int row = wn + j*16 + lr;
                bfr[j] = *(const bf16x8*)(Bs + row*64 + (((kk*4 + g) ^ (row & 7)) << 3));
            }
            #pragma unroll
            for (int i = 0; i < 4; ++i)
                #pragma unroll
                for (int j = 0; j < 4; ++j)
                    acc[i][j] = __builtin_amdgcn_mfma_f32_16x16x32_bf16(af[i], bfr[j], acc[i][j], 0, 0, 0);
        }
        __syncthreads();
    }

    const int sect = n0 >> 10;                 // 0=q, 1=k, 2=v
    float bq[4];
    #pragma unroll
    for (int j = 0; j < 4; ++j) bq[j] = bias[n0 + wn + j*16 + lr];

    if (sect < 2) {
        unsigned short* dst = sect ? kb : qb;
        const float sc = sect ? 1.0f : 0.125f * 1.44269504088896f;  // fold scale+log2e into q
        const int h = ((n0 & 1023) + wn) >> 6;
        #pragma unroll
        for (int i = 0; i < 4; ++i) {
            #pragma unroll
            for (int v = 0; v < 4; ++v) {
                int gm = m0 + wm + i*16 + g*4 + v;
                int b  = gm >> 11, n = gm & 2047;
                size_t base = ((size_t)(b*NUM_HEADS + h) * NTOK + n) << 6;
                #pragma unroll
                for (int j = 0; j < 4; ++j) {
                    int d = j*16 + lr;
                    float val = acc[i][j][v] + bq[j];
                    float vp  = acc[i][j^2][v] + bq[j^2];
                    float rot = (j < 2) ? -vp : vp;
                    float c = rcos[n*64 + d], s = rsin[n*64 + d];
                    dst[base + d] = f2bf((val * c + rot * s) * sc);
                }
            }
        }
    } else {
        unsigned short (*vt)[136] = (unsigned short (*)[136])smem;
        __syncthreads();
        #pragma unroll
        for (int i = 0; i < 4; ++i)
            #pragma unroll
            for (int j = 0; j < 4; ++j)
                #pragma unroll
                for (int v = 0; v < 4; ++v) {
                    int row = wm + i*16 + g*4 + v;
                    int c   = wn + j*16 + lr;
                    vt[c][row] = f2bf(acc[i][j][v] + bq[j]);
                }
        __syncthreads();
        const int b = m0 >> 11;
        const int nbase = m0 & 2047;
        #pragma unroll
        for (int it = 0; it < 8; ++it) {
            int c   = (tid >> 4) + it * 16;
            int sc2 = (n0 & 1023) + c;
            int hh  = sc2 >> 6, d = sc2 & 63;
            int nloc = (tid & 15) * 8;
            uint4 val = *(uint4*)&vt[c][nloc];
            *(uint4*)(vtb + ((size_t)(b*NUM_HEADS + hh) * HEAD_DIM + d) * NTOK + nbase + nloc) = val;
        }
    }
}

// ---------------- Kernel 2: flash attention (swapped-operand) ----------------
// 64 q-rows/block, 4 waves x 16 rows. S^T = mfma(K,Q): lane owns q = lane&15,
// kv = fn*16 + 4g + v -> scalar m/lsum, kv-contiguous P (b64 writes, b128 reads),
// lsum via ones-MFMA, O^T = mfma(V^T, P^T). LDS: K dbuf 16K | V dbuf 16K | P 8K.
__global__ __launch_bounds__(256, 4) void k_attn(
    const unsigned short* __restrict__ qb, const unsigned short* __restrict__ kb,
    const unsigned short* __restrict__ vtb, unsigned short* __restrict__ attnb)
{
    __shared__ __align__(16) char sb[40960];

    const int tid  = threadIdx.x;
    const int lane = tid & 63;
    const int w    = tid >> 6;
    const int g    = lane >> 4;
    const int lr   = lane & 15;
    const int q0   = blockIdx.x * 64;
    const int bh   = blockIdx.y;
    const int b    = bh >> 4, h = bh & 15;

    // ---- hoisted LDS byte offsets ----
    int kfoff[2][4], vfoff[2][4];
    #pragma unroll
    for (int kk = 0; kk < 2; ++kk)
        #pragma unroll
        for (int fn = 0; fn < 4; ++fn) {
            int row = fn*16 + lr;
            int sw  = ((kk*4 + g) ^ (row & 7)) << 4;
            kfoff[kk][fn] = row*128 + sw;
            vfoff[kk][fn] = 16384 + row*128 + sw;
        }
    const int pswz = (lr & 7) << 1;           // XOR on 8B-chunk bits 1-3
    int pwoff[4], proff[2];
    #pragma unroll
    for (int fn = 0; fn < 4; ++fn)
        pwoff[fn] = 32768 + w*2048 + lr*128 + (((fn*4 + g) ^ pswz) << 3);
    #pragma unroll
    for (int kk = 0; kk < 2; ++kk)
        proff[kk] = 32768 + w*2048 + lr*128 + (((kk*8 + g*2) ^ pswz) << 3);

    // ---- staging pointers ----
    const unsigned short* gk[2];
    const unsigned short* gv[2];
    char* dk[2]; char* dv[2];
    {
        const unsigned short* kbase = kb  + (size_t)bh * NTOK * 64;
        const unsigned short* vbase = vtb + (size_t)bh * HEAD_DIM * NTOK;
        #pragma unroll
        for (int hp = 0; hp < 2; ++hp) {
            int p   = tid + hp * 256;
            int row = p >> 3;
            int c   = (p & 7) ^ (row & 7);
            gk[hp] = kbase + row*64 + c*8;
            gv[hp] = vbase + (size_t)row*NTOK + c*8;
            dk[hp] = sb + p*16;
            dv[hp] = sb + 16384 + p*16;
        }
    }

    bf16x8 qa[2];
    {
        size_t qrow = ((size_t)bh * NTOK + q0 + w*16 + lr) * 64;
        #pragma unroll
        for (int kk = 0; kk < 2; ++kk)
            qa[kk] = *(const bf16x8*)(qb + qrow + kk*32 + g*8);
    }

    const f32x4 z4 = {0.f, 0.f, 0.f, 0.f};
    bf16x8 onesa;
    #pragma unroll
    for (int j = 0; j < 8; ++j) onesa[j] = (short)0x3F80;   // 1.0bf16

    f32x4 o2[4];       // O^T: lane holds q=lr, d = fd*16 + 4g + v
    f32x4 ol = z4;     // ones-MFMA row-sum accumulator (all components equal)
    float m_ = -1e30f;
    #pragma unroll
    for (int fd = 0; fd < 4; ++fd) o2[fd] = z4;

    // stage tile 0 into buffer 0
    #pragma unroll
    for (int hp = 0; hp < 2; ++hp) {
        gload16(gk[hp], (unsigned short*)dk[hp]);
        gload16(gv[hp], (unsigned short*)dv[hp]);
        gk[hp] += 4096; gv[hp] += 64;
    }
    __syncthreads();

#define ATTN_ITER(X, DO_STAGE)                                                   \
    {                                                                            \
        if (DO_STAGE) {                                                          \
            _Pragma("unroll")                                                    \
            for (int hp = 0; hp < 2; ++hp) {                                     \
                gload16(gk[hp], (unsigned short*)(dk[hp] + ((X) ^ 8192)));       \
                gload16(gv[hp], (unsigned short*)(dv[hp] + ((X) ^ 8192)));       \
                gk[hp] += 4096; gv[hp] += 64;                                    \
            }                                                                    \
        }                                                                        \
        f32x4 s_[4];                                                             \
        __builtin_amdgcn_s_setprio(1);                                           \
        _Pragma("unroll")                                                        \
        for (int fn = 0; fn < 4; ++fn) {                                         \
            bf16x8 kf = *(const bf16x8*)(sb + kfoff[0][fn] + (X));               \
            s_[fn] = __builtin_amdgcn_mfma_f32_16x16x32_bf16(kf, qa[0], z4, 0, 0, 0); \
        }                                                                        \
        _Pragma("unroll")                                                        \
        for (int fn = 0; fn < 4; ++fn) {                                         \
            bf16x8 kf = *(const bf16x8*)(sb + kfoff[1][fn] + (X));               \
            s_[fn] = __builtin_amdgcn_mfma_f32_16x16x32_bf16(kf, qa[1], s_[fn], 0, 0, 0); \
        }                                                                        \
        __builtin_amdgcn_s_setprio(0);                                           \
        float mmA = fmaxf(fmaxf(s_[0][0], s_[0][1]), fmaxf(s_[0][2], s_[0][3])); \
        float mmB = fmaxf(fmaxf(s_[1][0], s_[1][1]), fmaxf(s_[1][2], s_[1][3])); \
        float mmC = fmaxf(fmaxf(s_[2][0], s_[2][1]), fmaxf(s_[2][2], s_[2][3])); \
        float mmD = fmaxf(fmaxf(s_[3][0], s_[3][1]), fmaxf(s_[3][2], s_[3][3])); \
        float lmax = fmaxf(fmaxf(mmA, mmB), fmaxf(mmC, mmD));                    \
        if (__any(lmax > m_ + 8.f)) {                                            \
            float mx = fmaxf(lmax, __shfl_xor(lmax, 16));                        \
            mx = fmaxf(mx, __shfl_xor(mx, 32));                                  \
            float mn  = fmaxf(m_, mx);                                           \
            float scl = __builtin_amdgcn_exp2f(m_ - mn);                         \
            m_ = mn;                                                             \
            _Pragma("unroll")                                                    \
            for (int v = 0; v < 4; ++v) ol[v] *= scl;                            \
            _Pragma("unroll")                                                    \
            for (int fd = 0; fd < 4; ++fd)                                       \
                _Pragma("unroll")                                                \
                for (int v = 0; v < 4; ++v) o2[fd][v] *= scl;                    \
        }                                                                        \
        _Pragma("unroll")                                                        \
        for (int fn = 0; fn < 4; ++fn) {                                         \
            union { unsigned short us[4]; uint2 u2; } pk4;                       \
            _Pragma("unroll")                                                    \
            for (int v = 0; v < 4; ++v)                                          \
                pk4.us[v] = f2bf(__builtin_amdgcn_exp2f(s_[fn][v] - m_));        \
            *(uint2*)(sb + pwoff[fn]) = pk4.u2;                                  \
        }                                                                        \
        _Pragma("unroll")                                                        \
        for (int kk = 0; kk < 2; ++kk) {                                         \
            bf16x8 pb = *(const bf16x8*)(sb + proff[kk]);                        \
            bf16x8 vf[4];                                                        \
            _Pragma("unroll")                                                    \
            for (int fd = 0; fd < 4; ++fd)                                       \
                vf[fd] = *(const bf16x8*)(sb + vfoff[kk][fd] + (X));             \
            __builtin_amdgcn_s_setprio(1);                                       \
            ol = __builtin_amdgcn_mfma_f32_16x16x32_bf16(onesa, pb, ol, 0, 0, 0); \
            _Pragma("unroll")                                                    \
            for (int fd = 0; fd < 4; ++fd)                                       \
                o2[fd] = __builtin_amdgcn_mfma_f32_16x16x32_bf16(vf[fd], pb, o2[fd], 0, 0, 0); \
            __builtin_amdgcn_s_setprio(0);                                       \
        }                                                                        \
        __syncthreads();                                                         \
    }

    #pragma unroll 1
    for (int t = 0; t < NTOK/64; t += 2) {
        ATTN_ITER(0,    true);
        ATTN_ITER(8192, (t + 2 < NTOK/64));
    }
#undef ATTN_ITER

    // epilogue: lsum = ol[0] (MFMA already reduced across kv), pack b64 stores
    const float inv = 1.0f / ol[0];
    const size_t obase = ((size_t)(b*NTOK + q0 + w*16 + lr)) * DIM + h*HEAD_DIM + g*4;
    #pragma unroll
    for (int fd = 0; fd < 4; ++fd) {
        union { unsigned short us[4]; uint2 u2; } pk4;
        #pragma unroll
        for (int v = 0; v < 4; ++v) pk4.us[v] = f2bf(o2[fd][v] * inv);
        *(uint2*)(attnb + obase + fd*16) = pk4.u2;
    }
}

// ---------------- Kernel 3: output projection ----------------
__global__ __launch_bounds__(256) void k_proj(
    const unsigned short* __restrict__ a, const unsigned short* __restrict__ wb,
    const float* __restrict__ bias, float* __restrict__ out)
{
    __shared__ __align__(16) unsigned short As[8192];
    __shared__ __align__(16) unsigned short Bs[8192];

    const int tid  = threadIdx.x;
    const int lane = tid & 63;
    const int wid  = tid >> 6;
    const int lr   = lane & 15;
    const int g    = lane >> 4;
    const int wm   = (wid >> 1) * 64;
    const int wn   = (wid & 1) * 64;
    const int m0   = blockIdx.x * 128;
    const int n0   = blockIdx.y * 128;

    f32x4 acc[4][4];
    #pragma unroll
    for (int i = 0; i < 4; ++i)
        #pragma unroll
        for (int j = 0; j < 4; ++j) acc[i][j] = (f32x4){0.f, 0.f, 0.f, 0.f};

    for (int k0 = 0; k0 < DIM; k0 += 64) {
        #pragma unroll
        for (int it = 0; it < 4; ++it) {
            int p   = tid + it * 256;
            int row = p >> 3;
            int c   = (p & 7) ^ (row & 7);
            gload16(a  + (size_t)(m0 + row) * DIM + k0 + c*8, As + p*8);
            gload16(wb + (size_t)(n0 + row) * DIM + k0 + c*8, Bs + p*8);
        }
        __syncthreads();
        #pragma unroll
        for (int kk = 0; kk < 2; ++kk) {
            bf16x8 af[4], bfr[4];
            #pragma unroll
            for (int i = 0; i < 4; ++i) {
                int row = wm + i*16 + lr;
                af[i] = *(const bf16x8*)(As + row*64 + (((kk*4 + g) ^ (row & 7)) << 3));
            }
            #pragma unroll
            for (int j = 0; j < 4; ++j) {
                int row = wn + j*16 + lr;
                bfr[j] = *(const bf16x8*)(Bs + row*64 + (((kk*4 + g) ^ (row & 7)) << 3));
            }
            #pragma unroll
            for (int i = 0; i < 4; ++i)
                #pragma unroll
                for (int j = 0; j < 4; ++j)
                    acc[i][j] = __builtin_amdgcn_mfma_f32_16x16x32_bf16(af[i], bfr[j], acc[i][j], 0, 0, 0);
        }
        __syncthreads();
    }

    #pragma unroll
    for (int i = 0; i < 4; ++i)
        #pragma unroll
        for (int j = 0; j < 4; ++j)
            #pragma unroll
            for (int v = 0; v < 4; ++v) {
                int row = m0 + wm + i*16 + g*4 + v;
                int col = n0 + wn + j*16 + lr;
                out[(size_t)row * DIM + col] = acc[i][j][v] + bias[col];
            }
}

extern "C" void kernel_launch(void* const* d_in, const int* in_sizes, int n_in,
                              void* d_out, int out_size, void* d_ws, size_t ws_size,
                              hipStream_t stream)
{
    const float* x      = (const float*)d_in[0];
    const float* rcos   = (const float*)d_in[1];
    const float* rsin   = (const float*)d_in[2];
    const float* qkv_w  = (const float*)d_in[3];
    const float* qkv_b  = (const float*)d_in[4];
    const float* proj_w = (const float*)d_in[5];
    const float* proj_b = (const float*)d_in[6];
    float* out = (float*)d_out;

    const size_t BUF = (size_t)2 * NUM_HEADS * NTOK * HEAD_DIM;
    unsigned short* qb    = (unsigned short*)d_ws;
    unsigned short* kb    = qb + BUF;
    unsigned short* vtb   = kb + BUF;
    unsigned short* attnb = vtb + BUF;
    unsigned short* xbf   = attnb + BUF;
    unsigned short* wqkvb = xbf + (size_t)MTOT * DIM;
    unsigned short* wprjb = wqkvb + (size_t)3 * DIM * DIM;

    const int n0 = MTOT * DIM, n1 = 3 * DIM * DIM, n2 = DIM * DIM;
    k_conv3<<<dim3((n0 + n1 + n2) / 2048), 256, 0, stream>>>(
        x, xbf, n0, qkv_w, wqkvb, n1, proj_w, wprjb, n2);

    k_gemm_qkv<<<dim3(32, 24), 256, 0, stream>>>(xbf, wqkvb, qkv_b, rcos, rsin, qb, kb, vtb);
    k_attn<<<dim3(NTOK/64, 32), 256, 0, stream>>>(qb, kb, vtb, attnb);
    k_proj<<<dim3(32, 8), 256, 0, stream>>>(attnb, wprjb, proj_b, out);
}

// Round 7
// 121.548 us; speedup vs baseline: 2.8433x; 1.0523x over previous
//
#include <hip/hip_runtime.h>
#include <hip/hip_bf16.h>

#define NUM_HEADS 16
#define HEAD_DIM 64
#define DIM 1024
#define NTOK 2048
#define MTOT 4096

typedef __attribute__((ext_vector_type(8))) short bf16x8;
typedef __attribute__((ext_vector_type(4))) float f32x4;
typedef __attribute__((ext_vector_type(16))) float f32x16;
typedef __attribute__((ext_vector_type(2))) unsigned int uint2v;

__device__ __forceinline__ unsigned short f2bf(float f) {
    union { __hip_bfloat16 h; unsigned short u; } c;
    c.h = __float2bfloat16(f);
    return c.u;
}

__device__ __forceinline__ unsigned int packbf(float lo, float hi) {
    union { unsigned short us[2]; unsigned int u; } p;
    p.us[0] = f2bf(lo); p.us[1] = f2bf(hi);
    return p.u;
}

// permlane32_swap: a' = {a_lo, b_lo-from-partner}, b' = {a_hi-from-partner, b_hi}
__device__ __forceinline__ void plswap(unsigned int &a, unsigned int &b) {
#if __has_builtin(__builtin_amdgcn_permlane32_swap)
    uint2v r = __builtin_amdgcn_permlane32_swap(a, b, false, false);
    a = r[0]; b = r[1];
#else
    unsigned int pa = (unsigned int)__shfl_xor((int)a, 32);
    unsigned int pb = (unsigned int)__shfl_xor((int)b, 32);
    bool hi = (threadIdx.x & 32) != 0;
    unsigned int an = hi ? pb : a;
    unsigned int bn = hi ? b : pa;
    a = an; b = bn;
#endif
}

__device__ __forceinline__ void gload16(const unsigned short* g, unsigned short* l) {
    __builtin_amdgcn_global_load_lds(
        (const __attribute__((address_space(1))) void*)g,
        (__attribute__((address_space(3))) void*)l, 16, 0, 0);
}

// ---------------- Kernel 0: fused fp32 -> bf16 convert ----------------
__global__ __launch_bounds__(256) void k_conv3(
    const float* __restrict__ s0, unsigned short* __restrict__ d0, int n0,
    const float* __restrict__ s1, unsigned short* __restrict__ d1, int n1,
    const float* __restrict__ s2, unsigned short* __restrict__ d2, int n2)
{
    int blk = blockIdx.x;
    int b0 = n0 >> 11, b1 = n1 >> 11;
    const float* s; unsigned short* d; int i;
    if (blk < b0)            { s = s0; d = d0; i = blk; }
    else if (blk < b0 + b1)  { s = s1; d = d1; i = blk - b0; }
    else                     { s = s2; d = d2; i = blk - b0 - b1; }
    int idx = (i * 256 + threadIdx.x) * 8;
    float4 a = *(const float4*)(s + idx);
    float4 b = *(const float4*)(s + idx + 4);
    union { unsigned short us[8]; uint4 u4; } p;
    p.us[0] = f2bf(a.x); p.us[1] = f2bf(a.y); p.us[2] = f2bf(a.z); p.us[3] = f2bf(a.w);
    p.us[4] = f2bf(b.x); p.us[5] = f2bf(b.y); p.us[6] = f2bf(b.z); p.us[7] = f2bf(b.w);
    *(uint4*)(d + idx) = p.u4;
}

// ---------------- Kernel 1: QKV GEMM + bias + RoPE + layout (unchanged) ----------------
__global__ __launch_bounds__(256) void k_gemm_qkv(
    const unsigned short* __restrict__ xb, const unsigned short* __restrict__ wb,
    const float* __restrict__ bias, const float* __restrict__ rcos,
    const float* __restrict__ rsin,
    unsigned short* __restrict__ qb, unsigned short* __restrict__ kb,
    unsigned short* __restrict__ vtb)
{
    __shared__ __align__(16) unsigned char smem[34816];
    unsigned short* As = (unsigned short*)smem;
    unsigned short* Bs = (unsigned short*)(smem + 16384);

    const int tid  = threadIdx.x;
    const int lane = tid & 63;
    const int wid  = tid >> 6;
    const int lr   = lane & 15;
    const int g    = lane >> 4;
    const int wm   = (wid >> 1) * 64;
    const int wn   = (wid & 1) * 64;
    const int m0   = blockIdx.x * 128;
    const int n0   = blockIdx.y * 128;

    f32x4 acc[4][4];
    #pragma unroll
    for (int i = 0; i < 4; ++i)
        #pragma unroll
        for (int j = 0; j < 4; ++j) acc[i][j] = (f32x4){0.f, 0.f, 0.f, 0.f};

    for (int k0 = 0; k0 < DIM; k0 += 64) {
        #pragma unroll
        for (int it = 0; it < 4; ++it) {
            int p   = tid + it * 256;
            int row = p >> 3;
            int c   = (p & 7) ^ (row & 7);
            gload16(xb + (size_t)(m0 + row) * DIM + k0 + c*8, As + p*8);
            gload16(wb + (size_t)(n0 + row) * DIM + k0 + c*8, Bs + p*8);
        }
        __syncthreads();
        #pragma unroll
        for (int kk = 0; kk < 2; ++kk) {
            bf16x8 af[4], bfr[4];
            #pragma unroll
            for (int i = 0; i < 4; ++i) {
                int row = wm + i*16 + lr;
                af[i] = *(const bf16x8*)(As + row*64 + (((kk*4 + g) ^ (row & 7)) << 3));
            }
            #pragma unroll
            for (int j = 0; j < 4; ++j) {
                int row = wn + j*16 + lr;
                bfr[j] = *(const bf16x8*)(Bs + row*64 + (((kk*4 + g) ^ (row & 7)) << 3));
            }
            #pragma unroll
            for (int i = 0; i < 4; ++i)
                #pragma unroll
                for (int j = 0; j < 4; ++j)
                    acc[i][j] = __builtin_amdgcn_mfma_f32_16x16x32_bf16(af[i], bfr[j], acc[i][j], 0, 0, 0);
        }
        __syncthreads();
    }

    const int sect = n0 >> 10;
    float bq[4];
    #pragma unroll
    for (int j = 0; j < 4; ++j) bq[j] = bias[n0 + wn + j*16 + lr];

    if (sect < 2) {
        unsigned short* dst = sect ? kb : qb;
        const float sc = sect ? 1.0f : 0.125f * 1.44269504088896f;
        const int h = ((n0 & 1023) + wn) >> 6;
        #pragma unroll
        for (int i = 0; i < 4; ++i) {
            #pragma unroll
            for (int v = 0; v < 4; ++v) {
                int gm = m0 + wm + i*16 + g*4 + v;
                int b  = gm >> 11, n = gm & 2047;
                size_t base = ((size_t)(b*NUM_HEADS + h) * NTOK + n) << 6;
                #pragma unroll
                for (int j = 0; j < 4; ++j) {
                    int d = j*16 + lr;
                    float val = acc[i][j][v] + bq[j];
                    float vp  = acc[i][j^2][v] + bq[j^2];
                    float rot = (j < 2) ? -vp : vp;
                    float c = rcos[n*64 + d], s = rsin[n*64 + d];
                    dst[base + d] = f2bf((val * c + rot * s) * sc);
                }
            }
        }
    } else {
        unsigned short (*vt)[136] = (unsigned short (*)[136])smem;
        __syncthreads();
        #pragma unroll
        for (int i = 0; i < 4; ++i)
            #pragma unroll
            for (int j = 0; j < 4; ++j)
                #pragma unroll
                for (int v = 0; v < 4; ++v) {
                    int row = wm + i*16 + g*4 + v;
                    int c   = wn + j*16 + lr;
                    vt[c][row] = f2bf(acc[i][j][v] + bq[j]);
                }
        __syncthreads();
        const int b = m0 >> 11;
        const int nbase = m0 & 2047;
        #pragma unroll
        for (int it = 0; it < 8; ++it) {
            int c   = (tid >> 4) + it * 16;
            int sc2 = (n0 & 1023) + c;
            int hh  = sc2 >> 6, d = sc2 & 63;
            int nloc = (tid & 15) * 8;
            uint4 val = *(uint4*)&vt[c][nloc];
            *(uint4*)(vtb + ((size_t)(b*NUM_HEADS + hh) * HEAD_DIM + d) * NTOK + nbase + nloc) = val;
        }
    }
}

// ---------------- Kernel 2: flash attention (32x32 swapped, P in-register) ----------------
// 128 q/block, 4 waves x 32 q. S^T = mfma32(K,Q): lane owns q = lane&31, 32 kv
// split across the hi-pair. P -> PV B-frags via 16 cvt_pk + 8 permlane32_swap.
// LDS: K dbuf 16K | V dbuf 16K = 32K. 1 barrier/iter, x2 unrolled dbuf toggle.
__global__ __launch_bounds__(256, 2) void k_attn(
    const unsigned short* __restrict__ qb, const unsigned short* __restrict__ kb,
    const unsigned short* __restrict__ vtb, unsigned short* __restrict__ attnb)
{
    __shared__ __align__(16) char sb[32768];

    const int tid  = threadIdx.x;
    const int lane = tid & 63;
    const int w    = tid >> 6;
    const int hi   = lane >> 5;
    const int lc   = lane & 31;
    const int q0   = blockIdx.x * 128;
    const int bh   = blockIdx.y;
    const int b    = bh >> 4, h = bh & 15;

    // hoisted LDS read offsets (16B-chunk XOR swizzle, matches staging)
    int kfoff[2][4], vfoff[2][4];
    #pragma unroll
    for (int s = 0; s < 2; ++s)
        #pragma unroll
        for (int ks = 0; ks < 4; ++ks) {
            int row = 32*s + lc;
            kfoff[s][ks] = row*128 + (((2*ks + hi) ^ (row & 7)) << 4);
            vfoff[s][ks] = 16384 + row*128 + (((2*ks + hi) ^ (row & 7)) << 4);
        }

    // staging pointers (inverse-swizzled global source, linear LDS dest)
    const unsigned short* gk[2];
    const unsigned short* gv[2];
    char* dk[2]; char* dv[2];
    {
        const unsigned short* kbase = kb  + (size_t)bh * NTOK * 64;
        const unsigned short* vbase = vtb + (size_t)bh * HEAD_DIM * NTOK;
        #pragma unroll
        for (int hp = 0; hp < 2; ++hp) {
            int p   = tid + hp * 256;
            int row = p >> 3;
            int c   = (p & 7) ^ (row & 7);
            gk[hp] = kbase + row*64 + c*8;
            gv[hp] = vbase + (size_t)row*NTOK + c*8;
            dk[hp] = sb + p*16;
            dv[hp] = sb + 16384 + p*16;
        }
    }

    // Q fragments (B-operand): lane holds Q[q0+w*32+lc][16ks + 8hi + j]
    bf16x8 qa[4];
    {
        size_t qrow = ((size_t)bh * NTOK + q0 + w*32 + lc) * 64;
        #pragma unroll
        for (int ks = 0; ks < 4; ++ks)
            qa[ks] = *(const bf16x8*)(qb + qrow + ks*16 + hi*8);
    }

    const f32x16 z16 = {0.f,0.f,0.f,0.f, 0.f,0.f,0.f,0.f, 0.f,0.f,0.f,0.f, 0.f,0.f,0.f,0.f};
    f32x16 o2[2];          // O^T: lane q=lc, d = 32*sd + (r&3)+8*(r>>2)+4*hi
    o2[0] = z16; o2[1] = z16;
    float m_ = -1e30f, lsum = 0.f;

    // stage tile 0 into buffer 0
    #pragma unroll
    for (int hp = 0; hp < 2; ++hp) {
        gload16(gk[hp], (unsigned short*)dk[hp]);
        gload16(gv[hp], (unsigned short*)dv[hp]);
        gk[hp] += 4096; gv[hp] += 64;
    }
    __syncthreads();

#define ATTN_ITER(X, DO_STAGE)                                                   \
    {                                                                            \
        if (DO_STAGE) {                                                          \
            _Pragma("unroll")                                                    \
            for (int hp = 0; hp < 2; ++hp) {                                     \
                gload16(gk[hp], (unsigned short*)(dk[hp] + ((X) ^ 8192)));       \
                gload16(gv[hp], (unsigned short*)(dv[hp] + ((X) ^ 8192)));       \
                gk[hp] += 4096; gv[hp] += 64;                                    \
            }                                                                    \
        }                                                                        \
        /* QK^T: S^T[kv][q], kv-halves s=0,1 */                                  \
        f32x16 S0, S1;                                                           \
        {                                                                        \
            bf16x8 kf0[4], kf1[4];                                               \
            _Pragma("unroll")                                                    \
            for (int ks = 0; ks < 4; ++ks) {                                     \
                kf0[ks] = *(const bf16x8*)(sb + kfoff[0][ks] + (X));             \
                kf1[ks] = *(const bf16x8*)(sb + kfoff[1][ks] + (X));             \
            }                                                                    \
            __builtin_amdgcn_s_setprio(1);                                       \
            S0 = __builtin_amdgcn_mfma_f32_32x32x16_bf16(kf0[0], qa[0], z16, 0, 0, 0); \
            S1 = __builtin_amdgcn_mfma_f32_32x32x16_bf16(kf1[0], qa[0], z16, 0, 0, 0); \
            _Pragma("unroll")                                                    \
            for (int ks = 1; ks < 4; ++ks) {                                     \
                S0 = __builtin_amdgcn_mfma_f32_32x32x16_bf16(kf0[ks], qa[ks], S0, 0, 0, 0); \
                S1 = __builtin_amdgcn_mfma_f32_32x32x16_bf16(kf1[ks], qa[ks], S1, 0, 0, 0); \
            }                                                                    \
            __builtin_amdgcn_s_setprio(0);                                       \
        }                                                                        \
        /* lazy max over this lane's 32 scores (log2 domain) */                  \
        float t[16];                                                             \
        _Pragma("unroll")                                                        \
        for (int r = 0; r < 16; ++r) t[r] = fmaxf(S0[r], S1[r]);                 \
        _Pragma("unroll")                                                        \
        for (int st = 8; st > 0; st >>= 1)                                       \
            _Pragma("unroll")                                                    \
            for (int i = 0; i < 8; ++i) if (i < st) t[i] = fmaxf(t[i], t[i + st]); \
        float lmax = t[0];                                                       \
        if (__any(lmax > m_ + 8.f)) {                                            \
            float mx = fmaxf(lmax, __shfl_xor(lmax, 32));                        \
            float mn = fmaxf(m_, mx);                                            \
            float scl = __builtin_amdgcn_exp2f(m_ - mn);                         \
            m_ = mn;                                                             \
            lsum *= scl;                                                         \
            o2[0] *= scl; o2[1] *= scl;                                          \
        }                                                                        \
        /* P = exp2(S - m), in-lane sum */                                       \
        _Pragma("unroll")                                                        \
        for (int r = 0; r < 16; ++r) {                                           \
            S0[r] = __builtin_amdgcn_exp2f(S0[r] - m_);                          \
            S1[r] = __builtin_amdgcn_exp2f(S1[r] - m_);                          \
        }                                                                        \
        _Pragma("unroll")                                                        \
        for (int r = 0; r < 16; ++r) t[r] = S0[r] + S1[r];                       \
        _Pragma("unroll")                                                        \
        for (int st = 8; st > 0; st >>= 1)                                       \
            _Pragma("unroll")                                                    \
            for (int i = 0; i < 8; ++i) if (i < st) t[i] += t[i + st];           \
        lsum += t[0];                                                            \
        /* P -> PV B-fragments: cvt_pk pairs + permlane32_swap routing */        \
        unsigned int dwA[2][4], dwB[2][4];                                       \
        _Pragma("unroll")                                                        \
        for (int c = 0; c < 4; ++c) {                                            \
            dwA[0][c] = packbf(S0[4*c],     S0[4*c + 1]);                        \
            dwB[0][c] = packbf(S0[4*c + 2], S0[4*c + 3]);                        \
            dwA[1][c] = packbf(S1[4*c],     S1[4*c + 1]);                        \
            dwB[1][c] = packbf(S1[4*c + 2], S1[4*c + 3]);                        \
        }                                                                        \
        bf16x8 pB[4];                                                            \
        _Pragma("unroll")                                                        \
        for (int t16 = 0; t16 < 4; ++t16) {                                      \
            int s = t16 >> 1, u = t16 & 1;                                       \
            unsigned int a0 = dwA[s][2*u], b0 = dwA[s][2*u + 1];                 \
            unsigned int a1 = dwB[s][2*u], b1 = dwB[s][2*u + 1];                 \
            plswap(a0, b0);                                                      \
            plswap(a1, b1);                                                      \
            union { unsigned int u4[4]; bf16x8 v; } pk;                          \
            pk.u4[0] = a0; pk.u4[1] = a1; pk.u4[2] = b0; pk.u4[3] = b1;          \
            pB[t16] = pk.v;                                                      \
        }                                                                        \
        /* PV: O^T += V^T[d][kv-slice] . P^T[kv-slice][q] */                     \
        _Pragma("unroll")                                                        \
        for (int t16 = 0; t16 < 4; ++t16) {                                      \
            bf16x8 vf0 = *(const bf16x8*)(sb + vfoff[0][t16] + (X));             \
            bf16x8 vf1 = *(const bf16x8*)(sb + vfoff[1][t16] + (X));             \
            __builtin_amdgcn_s_setprio(1);                                       \
            o2[0] = __builtin_amdgcn_mfma_f32_32x32x16_bf16(vf0, pB[t16], o2[0], 0, 0, 0); \
            o2[1] = __builtin_amdgcn_mfma_f32_32x32x16_bf16(vf1, pB[t16], o2[1], 0, 0, 0); \
            __builtin_amdgcn_s_setprio(0);                                       \
        }                                                                        \
        __syncthreads();                                                         \
    }

    #pragma unroll 1
    for (int tt = 0; tt < NTOK/64; tt += 2) {
        ATTN_ITER(0,    true);
        ATTN_ITER(8192, (tt + 2 < NTOK/64));
    }
#undef ATTN_ITER

    // epilogue: pair-reduce lsum across hi halves (same q), normalize, store
    lsum += __shfl_xor(lsum, 32);
    const float inv = 1.0f / lsum;
    const size_t obase = ((size_t)(b*NTOK + q0 + w*32 + lc)) * DIM + h*HEAD_DIM + hi*4;
    #pragma unroll
    for (int sd = 0; sd < 2; ++sd)
        #pragma unroll
        for (int c = 0; c < 4; ++c) {
            union { unsigned short us[4]; uint2 u2; } pk4;
            #pragma unroll
            for (int v = 0; v < 4; ++v) pk4.us[v] = f2bf(o2[sd][4*c + v] * inv);
            *(uint2*)(attnb + obase + sd*32 + c*8) = pk4.u2;
        }
}

// ---------------- Kernel 3: output projection (128x64 tile, 2 blocks/CU) ----------------
__global__ __launch_bounds__(256) void k_proj(
    const unsigned short* __restrict__ a, const unsigned short* __restrict__ wb,
    const float* __restrict__ bias, float* __restrict__ out)
{
    __shared__ __align__(16) unsigned short As[8192];   // [128][64] swizzled
    __shared__ __align__(16) unsigned short Bs[4096];   // [64][64] swizzled

    const int tid  = threadIdx.x;
    const int lane = tid & 63;
    const int wid  = tid >> 6;
    const int lr   = lane & 15;
    const int g    = lane >> 4;
    const int wm   = (wid & 1) * 64;
    const int wn   = (wid >> 1) * 32;
    const int m0   = blockIdx.x * 128;
    const int n0   = blockIdx.y * 64;

    f32x4 acc[4][2];
    #pragma unroll
    for (int i = 0; i < 4; ++i)
        #pragma unroll
        for (int j = 0; j < 2; ++j) acc[i][j] = (f32x4){0.f, 0.f, 0.f, 0.f};

    for (int k0 = 0; k0 < DIM; k0 += 64) {
        #pragma unroll
        for (int it = 0; it < 4; ++it) {
            int p   = tid + it * 256;
            int row = p >> 3;
            int c   = (p & 7) ^ (row & 7);
            gload16(a + (size_t)(m0 + row) * DIM + k0 + c*8, As + p*8);
        }
        #pragma unroll
        for (int it = 0; it < 2; ++it) {
            int p   = tid + it * 256;
            int row = p >> 3;
            int c   = (p & 7) ^ (row & 7);
            gload16(wb + (size_t)(n0 + row) * DIM + k0 + c*8, Bs + p*8);
        }
        __syncthreads();
        #pragma unroll
        for (int kk = 0; kk < 2; ++kk) {
            bf16x8 af[4], bfr[2];
            #pragma unroll
            for (int i = 0; i < 4; ++i) {
                int row = wm + i*16 + lr;
                af[i] = *(const bf16x8*)(As + row*64 + (((kk*4 + g) ^ (row & 7)) << 3));
            }
            #pragma unroll
            for (int j = 0; j < 2; ++j) {
                int row = wn + j*16 + lr;
                bfr[j] = *(const bf16x8*)(Bs + row*64 + (((kk*4 + g) ^ (row & 7)) << 3));
            }
            #pragma unroll
            for (int i = 0; i < 4; ++i)
                #pragma unroll
                for (int j = 0; j < 2; ++j)
                    acc[i][j] = __builtin_amdgcn_mfma_f32_16x16x32_bf16(af[i], bfr[j], acc[i][j], 0, 0, 0);
        }
        __syncthreads();
    }

    #pragma unroll
    for (int i = 0; i < 4; ++i)
        #pragma unroll
        for (int j = 0; j < 2; ++j)
            #pragma unroll
            for (int v = 0; v < 4; ++v) {
                int row = m0 + wm + i*16 + g*4 + v;
                int col = n0 + wn + j*16 + lr;
                out[(size_t)row * DIM + col] = acc[i][j][v] + bias[col];
            }
}

extern "C" void kernel_launch(void* const* d_in, const int* in_sizes, int n_in,
                              void* d_out, int out_size, void* d_ws, size_t ws_size,
                              hipStream_t stream)
{
    const float* x      = (const float*)d_in[0];
    const float* rcos   = (const float*)d_in[1];
    const float* rsin   = (const float*)d_in[2];
    const float* qkv_w  = (const float*)d_in[3];
    const float* qkv_b  = (const float*)d_in[4];
    const float* proj_w = (const float*)d_in[5];
    const float* proj_b = (const float*)d_in[6];
    float* out = (float*)d_out;

    const size_t BUF = (size_t)2 * NUM_HEADS * NTOK * HEAD_DIM;
    unsigned short* qb    = (unsigned short*)d_ws;
    unsigned short* kb    = qb + BUF;
    unsigned short* vtb   = kb + BUF;
    unsigned short* attnb = vtb + BUF;
    unsigned short* xbf   = attnb + BUF;
    unsigned short* wqkvb = xbf + (size_t)MTOT * DIM;
    unsigned short* wprjb = wqkvb + (size_t)3 * DIM * DIM;

    const int n0 = MTOT * DIM, n1 = 3 * DIM * DIM, n2 = DIM * DIM;
    k_conv3<<<dim3((n0 + n1 + n2) / 2048), 256, 0, stream>>>(
        x, xbf, n0, qkv_w, wqkvb, n1, proj_w, wprjb, n2);

    k_gemm_qkv<<<dim3(32, 24), 256, 0, stream>>>(xbf, wqkvb, qkv_b, rcos, rsin, qb, kb, vtb);
    k_attn<<<dim3(NTOK/128, 32), 256, 0, stream>>>(qb, kb, vtb, attnb);
    k_proj<<<dim3(32, 16), 256, 0, stream>>>(attnb, wprjb, proj_b, out);
}